// Round 4
// baseline (92435.468 us; speedup 1.0000x reference)
//
#include <hip/hip_runtime.h>
#include <math.h>

// ---------------- problem constants ----------------
// B=12, T=2048, D=260, V=256, R=280, 3D=780
#define NB1 13          // cooperative scan workgroups (13*20 = 260 dims)

// ---------------- workspace layout (float offsets) ----------------
#define OFF_XTAB  0            // [256][780]  soma_w@Wih.T+bih table
#define OFF_KEYS  199680       // [280][260]  l2norm(rel_keys)
#define OFF_SNT   272480       // [260][256]  l2norm(soma_w) transposed
#define OFF_PFCT  339040       // [520][260]  pfc_W transposed
#define OFF_PF    474240       // [2048][12][260] p_f, overlaid later by latf
#define OFF_OUTS  6864000      // [12][2048][260] outs (head doubles as sync flags)
#define OFF_HBUF  13253760     // [2][3120] scan1 h double buffer
#define OFF_LATB  13260000     // [2][3120] scan2 latent double buffer
#define OFF_HMB   13266240     // [2][3120] scan2 h_mono double buffer
#define WS_FLOATS 13272544

#define FLAG_STRIDE 32
#define NFLAG_INTS  (2*NB1*FLAG_STRIDE)

// ---------------- output layout (float offsets) ----------------
#define OUT_HF 6291456
#define OUT_HM 6294576
#define OUT_DS 6297696

// write-through (coherence-point) ops: relaxed agent atomics — no wbl2/inv.
__device__ inline void st_wt(float* p, float v) {
  __hip_atomic_store(p, v, __ATOMIC_RELAXED, __HIP_MEMORY_SCOPE_AGENT);
}
// 8-byte coherent load: one LLC transaction for two floats.
__device__ inline float2 ld_wt8(const float* p) {
  unsigned long long u = __hip_atomic_load((const unsigned long long*)p,
                                           __ATOMIC_RELAXED, __HIP_MEMORY_SCOPE_AGENT);
  union { unsigned long long u; float2 f; } c; c.u = u;
  return c.f;
}

__device__ inline float block_sum256(float v, float* red) {
  #pragma unroll
  for (int m = 32; m; m >>= 1) v += __shfl_xor(v, m);
  int w = threadIdx.x >> 6;
  __syncthreads();
  if ((threadIdx.x & 63) == 0) red[w] = v;
  __syncthreads();
  return red[0] + red[1] + red[2] + red[3];
}

// contention-free, maintenance-op-free grid barrier (13 flags).
__device__ inline void post_and_wait(int* flags, int mywg, int target, bool skip_wait) {
  __syncthreads();
  int tid = threadIdx.x;
  if (tid == 0) {
    asm volatile("s_waitcnt vmcnt(0)" ::: "memory");
    __hip_atomic_store(&flags[mywg*FLAG_STRIDE], target, __ATOMIC_RELAXED, __HIP_MEMORY_SCOPE_AGENT);
  }
  if (!skip_wait) {
    if (tid < 64) {
      int fi = (tid < NB1 ? tid : NB1-1)*FLAG_STRIDE;
      for (;;) {
        int v = __hip_atomic_load(&flags[fi], __ATOMIC_RELAXED, __HIP_MEMORY_SCOPE_AGENT);
        if (__all(v >= target)) break;
      }
    }
    __syncthreads();
  }
}

// ============ K0: prep tables (xtab, keys_n, soma_n^T, pfc_W^T) ============
__global__ __launch_bounds__(256) void k0_prep(
    const float* __restrict__ soma_w, const float* __restrict__ gWih,
    const float* __restrict__ gbih, const float* __restrict__ rel_keys,
    const float* __restrict__ pfc_W, float* __restrict__ ws) {
  int bid = blockIdx.x, tid = threadIdx.x;
  __shared__ float row[260];
  __shared__ float red[4];
  if (bid < 256) {                    // xin table row v
    int v = bid;
    row[tid] = soma_w[v*260 + tid];
    if (tid < 4) row[256+tid] = soma_w[v*260 + 256 + tid];
    __syncthreads();
    for (int n = tid; n < 780; n += 256) {
      const float* w = gWih + n*260;
      float acc = gbih[n];
      for (int k = 0; k < 260; ++k) acc += row[k]*w[k];
      ws[OFF_XTAB + v*780 + n] = acc;
    }
  } else if (bid < 536) {             // keys_n row r
    int r = bid - 256;
    row[tid] = rel_keys[r*260 + tid];
    if (tid < 4) row[256+tid] = rel_keys[r*260 + 256 + tid];
    __syncthreads();
    float v0 = row[tid], v1 = (tid < 4) ? row[256+tid] : 0.f;
    float ss = block_sum256(v0*v0 + v1*v1, red);
    float sc = 1.f / fmaxf(sqrtf(ss), 1e-12f);
    ws[OFF_KEYS + r*260 + tid] = v0*sc;
    if (tid < 4) ws[OFF_KEYS + r*260 + 256 + tid] = v1*sc;
  } else if (bid < 792) {             // soma_n transposed, col v
    int v = bid - 536;
    row[tid] = soma_w[v*260 + tid];
    if (tid < 4) row[256+tid] = soma_w[v*260 + 256 + tid];
    __syncthreads();
    float v0 = row[tid], v1 = (tid < 4) ? row[256+tid] : 0.f;
    float ss = block_sum256(v0*v0 + v1*v1, red);
    float sc = 1.f / fmaxf(sqrtf(ss), 1e-12f);
    ws[OFF_SNT + tid*256 + v] = v0*sc;
    if (tid < 4) ws[OFF_SNT + (256+tid)*256 + v] = v1*sc;
  } else {                            // pfc_W transpose row kk
    int kk = bid - 792;               // 0..519
    for (int d = tid; d < 260; d += 256)
      ws[OFF_PFCT + kk*260 + d] = pfc_W[d*520 + kk];
  }
}

// ============ K2: scan1 (GRU over T), 13 WGs x 1024 thr ============
// groups (tid>>4): g<60 -> (dl=g/3, gate=g%3) matvec of Whh rows; combine by tid<240.
__global__ __launch_bounds__(1024) void k2_scan1(
    const int* __restrict__ x, const float* __restrict__ h_f,
    const float* __restrict__ gWhh, const float* __restrict__ gbhh,
    float* __restrict__ ws, int* __restrict__ flags, float* __restrict__ out) {
  int bid = blockIdx.x, tid = threadIdx.x;
  int g = tid >> 4, l16 = tid & 15;
  int k0 = l16*20;
  int dl = g/3, gate = g - dl*3;      // valid for g<60
  float w1[20];
  if (g < 60) {
    const float* wr = gWhh + (gate*260 + bid*20 + dl)*260;
    #pragma unroll
    for (int kk = 0; kk < 20; ++kk) {
      int k = k0 + kk;
      w1[kk] = (k < 260) ? wr[k] : 0.f;
    }
  } else {
    #pragma unroll
    for (int kk = 0; kk < 20; ++kk) w1[kk] = 0.f;
  }
  __shared__ float h_lds[12][320];
  __shared__ float gl[20][3][12];
  __shared__ float bhh_l[20][3];
  for (int idx = tid; idx < 12*320; idx += 1024) ((float*)h_lds)[idx] = 0.f;
  if (tid < 60) {
    int dl2 = tid/3, g2 = tid - dl2*3;
    bhh_l[dl2][g2] = gbhh[g2*260 + bid*20 + dl2];
  }
  float* hbuf = ws + OFF_HBUF;
  float* pf   = ws + OFF_PF;
  const float* xtab = ws + OFF_XTAB;
  // t=0 state: h_f (zeros by spec, but load anyway)
  for (int idx = tid; idx < 780; idx += 1024) {
    int i = idx/65, j = idx - i*65;
    ((float4*)&h_lds[i][0])[j] = ((const float4*)(h_f + i*260))[j];
  }
  __syncthreads();
  int cur = 0;
  for (int t = 0; t < 2048; ++t) {
    if (g < 60) {
      #pragma unroll
      for (int i = 0; i < 12; ++i) {
        const float* hp = &h_lds[i][k0];
        float a = 0.f;
        #pragma unroll
        for (int kk = 0; kk < 20; ++kk) a += w1[kk]*hp[kk];
        #pragma unroll
        for (int m = 8; m; m >>= 1) a += __shfl_xor(a, m);
        if (l16 == 0) gl[dl][gate][i] = a;
      }
    }
    __syncthreads();
    if (tid < 240) {
      int dl2 = tid/12, i = tid - dl2*12;
      int d = bid*20 + dl2;
      int xi = x[i*2048 + t];
      const float* xrow = xtab + xi*780;
      float xr = xrow[d], xz = xrow[260+d], xn = xrow[520+d];
      float hr = gl[dl2][0][i] + bhh_l[dl2][0];
      float hz = gl[dl2][1][i] + bhh_l[dl2][1];
      float hn = gl[dl2][2][i] + bhh_l[dl2][2];
      float rg = 1.f/(1.f + expf(-(xr+hr)));
      float zg = 1.f/(1.f + expf(-(xz+hz)));
      float ng = tanhf(xn + rg*hn);
      float hprev = h_lds[i][d];
      float hnew = (1.f - zg)*ng + zg*hprev;
      st_wt(hbuf + (cur^1)*3120 + i*260 + d, hnew);
      pf[(t*12 + i)*260 + d] = hnew;
      if (t == 2047) out[OUT_HF + i*260 + d] = hnew;
    }
    post_and_wait(flags, bid, t+1, t == 2047);
    if (t < 2047) {
      const float* hs = hbuf + (cur^1)*3120;
      for (int jj = tid; jj < 1560; jj += 1024) {
        int i = jj/130, q = jj - i*130;
        float2 v = ld_wt8(hs + i*260 + q*2);
        h_lds[i][q*2]   = v.x;
        h_lds[i][q*2+1] = v.y;
      }
      __syncthreads();
    }
    cur ^= 1;
  }
}

// ============ K3: scan2 recurrent core, 13 WGs x 1024 thr ============
// groups: g<40 -> (dl=g>>1, sel=g&1) 3-gate matvec (wi on lat / wh on hm);
//         g in [40,52) -> vol dot for row g-40; combine by tid<240.
__global__ __launch_bounds__(1024) void k3_scan2(
    const float* __restrict__ h_mono, const float* __restrict__ wWih,
    const float* __restrict__ wWhh, const float* __restrict__ wbih,
    const float* __restrict__ wbhh, const float* __restrict__ vgW,
    const float* __restrict__ vgb, const int* __restrict__ surprise,
    const int* __restrict__ dsteps, float* __restrict__ ws,
    int* __restrict__ flags, float* __restrict__ out) {
  int bid = blockIdx.x, tid = threadIdx.x;
  int g = tid >> 4, l16 = tid & 15;
  int k0 = l16*20;
  int dl = g >> 1, sel = g & 1;       // valid for g<40
  float w3[3][20];
  if (g < 40) {
    const float* M = sel ? wWhh : wWih;
    #pragma unroll
    for (int gate = 0; gate < 3; ++gate) {
      const float* wr = M + (gate*260 + bid*20 + dl)*260;
      #pragma unroll
      for (int kk = 0; kk < 20; ++kk) {
        int k = k0 + kk;
        w3[gate][kk] = (k < 260) ? wr[k] : 0.f;
      }
    }
  } else {
    #pragma unroll
    for (int gate = 0; gate < 3; ++gate)
      #pragma unroll
      for (int kk = 0; kk < 20; ++kk) w3[gate][kk] = 0.f;
  }
  __shared__ float lat[12][320];
  __shared__ float hm[12][320];
  __shared__ float gl2[20][2][3][12];
  __shared__ float vol_l[12];
  __shared__ float vg_l[320];
  __shared__ float bih_l[20][3], bhh_l[20][3];
  for (int idx = tid; idx < 12*320; idx += 1024) { ((float*)lat)[idx] = 0.f; ((float*)hm)[idx] = 0.f; }
  if (tid < 320) vg_l[tid] = (tid < 260) ? vgW[tid] : 0.f;
  if (tid < 60) {
    int dl2 = tid/3, g2 = tid - dl2*3;
    bih_l[dl2][g2] = wbih[g2*260 + bid*20 + dl2];
    bhh_l[dl2][g2] = wbhh[g2*260 + bid*20 + dl2];
  }
  int ds = dsteps[0]; if (ds < 1) ds = 1;
  float sb = logf(fmaxf(1.f, (float)surprise[0]));
  float vgb_sb = vgb[0] + sb;
  float will_r = 0.f, cost_r = 0.f;
  const float costfac = 0.12f/2048.f;
  float* pf   = ws + OFF_PF;
  float* latb = ws + OFF_LATB;
  float* hmb  = ws + OFF_HMB;
  // hm init from h_mono
  for (int idx = tid; idx < 780; idx += 1024) {
    int i = idx/65, j = idx - i*65;
    ((float4*)&hm[i][0])[j] = ((const float4*)(h_mono + i*260))[j];
  }
  int p = 0;
  __syncthreads();
  for (int t = 0; t < 2048; ++t) {
    // latent := p_f[t] (written by k2, kernel boundary -> normal cached loads)
    const float* lsrc = pf + t*3120;
    for (int idx = tid; idx < 780; idx += 1024) {
      int i = idx/65, j = idx - i*65;
      ((float4*)&lat[i][0])[j] = ((const float4*)(lsrc + i*260))[j];
    }
    __syncthreads();
    for (int s = 0; s < ds; ++s) {
      bool last = (t == 2047) && (s == ds-1);
      // phase a: gate matvecs (g<40) and vol dots (g in [40,52)) in parallel
      if (g < 40) {
        const float (*src)[320] = sel ? hm : lat;
        #pragma unroll
        for (int i = 0; i < 12; ++i) {
          const float* sp = &src[i][k0];
          float a0 = 0.f, a1 = 0.f, a2 = 0.f;
          #pragma unroll
          for (int kk = 0; kk < 20; ++kk) {
            float v = sp[kk];
            a0 += w3[0][kk]*v; a1 += w3[1][kk]*v; a2 += w3[2][kk]*v;
          }
          #pragma unroll
          for (int m = 8; m; m >>= 1) {
            a0 += __shfl_xor(a0,m); a1 += __shfl_xor(a1,m); a2 += __shfl_xor(a2,m);
          }
          if (l16 == 0) {
            gl2[dl][sel][0][i] = a0; gl2[dl][sel][1][i] = a1; gl2[dl][sel][2][i] = a2;
          }
        }
      } else if (g < 52) {
        int i = g - 40;
        const float* lp = &lat[i][k0];
        float pv = 0.f;
        #pragma unroll
        for (int kk = 0; kk < 20; ++kk) pv += vg_l[k0+kk]*lp[kk];
        #pragma unroll
        for (int m = 8; m; m >>= 1) pv += __shfl_xor(pv, m);
        if (l16 == 0) vol_l[i] = 1.f/(1.f + expf(-(pv + vgb_sb)));
      }
      __syncthreads();
      // phase b: combine
      if (tid < 240) {
        int dl2 = tid/12, i = tid - dl2*12;
        int d = bid*20 + dl2;
        float xr = gl2[dl2][0][0][i] + bih_l[dl2][0];
        float xz = gl2[dl2][0][1][i] + bih_l[dl2][1];
        float xn = gl2[dl2][0][2][i] + bih_l[dl2][2];
        float hr = gl2[dl2][1][0][i] + bhh_l[dl2][0];
        float hz = gl2[dl2][1][1][i] + bhh_l[dl2][1];
        float hn = gl2[dl2][1][2][i] + bhh_l[dl2][2];
        float rg = 1.f/(1.f + expf(-(xr+hr)));
        float zg = 1.f/(1.f + expf(-(xz+hz)));
        float ng = tanhf(xn + rg*hn);
        float hmold = hm[i][d];
        float hmnew = (1.f - zg)*ng + zg*hmold;
        float latnew = lat[i][d] + hmnew * vol_l[i];
        st_wt(hmb  + (p^1)*3120 + i*260 + d, hmnew);
        st_wt(latb + (p^1)*3120 + i*260 + d, latnew);
        if (s == ds-1) {
          pf[(t*12 + i)*260 + d] = latnew;   // latf overlay (>=1 barrier after reads)
          if (t == 2047) out[OUT_HM + i*260 + d] = hmnew;
        }
      }
      if (tid == 0) {
        float vs = 0.f;
        #pragma unroll
        for (int i = 0; i < 12; ++i) vs += vol_l[i];
        float vm = vs * (1.f/12.f);
        will_r += vm;
        cost_r += vm * costfac;
      }
      post_and_wait(flags, bid, t*ds + s + 1, last);
      if (!last) {
        const float* hs2 = hmb + (p^1)*3120;
        if (s < ds-1) {
          const float* ls2 = latb + (p^1)*3120;
          for (int jj = tid; jj < 1560; jj += 1024) {
            int i = jj/130, q = jj - i*130;
            float2 a = ld_wt8(ls2 + i*260 + q*2);
            float2 b = ld_wt8(hs2 + i*260 + q*2);
            lat[i][q*2] = a.x; lat[i][q*2+1] = a.y;
            hm[i][q*2]  = b.x; hm[i][q*2+1]  = b.y;
          }
        } else {
          for (int jj = tid; jj < 1560; jj += 1024) {
            int i = jj/130, q = jj - i*130;
            float2 b = ld_wt8(hs2 + i*260 + q*2);
            hm[i][q*2]  = b.x; hm[i][q*2+1]  = b.y;
          }
        }
        __syncthreads();
      }
      p ^= 1;
    }
  }
  if (bid == 0 && tid == 0) {
    out[OUT_DS]   = (float)dsteps[0];
    out[OUT_DS+1] = cost_r;
    out[OUT_DS+2] = will_r / (2048.f * (float)ds);
  }
}

// ============ K4: per-t tail (attention + pfc + LN + GELU) ============
__global__ __launch_bounds__(256) void k4_tail(
    const float* __restrict__ rel_vals, const float* __restrict__ pfc_b,
    const float* __restrict__ pfc_g, const float* __restrict__ pfc_beta,
    float* __restrict__ ws) {
  int t = blockIdx.x, tid = threadIdx.x;
  int tg = tid >> 4, l16 = tid & 15;
  __shared__ float lat[12][260];
  __shared__ float sc[12][280];
  __shared__ float ctx[12][260];
  __shared__ float zb[12][260];
  __shared__ float qinv[12];
  __shared__ float mu[12], rstd[12];
  const float* lsrc = ws + OFF_PF + t*3120;   // latf
  for (int idx = tid; idx < 780; idx += 256)
    ((float4*)lat)[idx] = ((const float4*)lsrc)[idx];
  __syncthreads();
  if (tg < 12) {
    float ss = 0;
    for (int k = l16; k < 260; k += 16) { float v = lat[tg][k]; ss += v*v; }
    #pragma unroll
    for (int m = 8; m; m >>= 1) ss += __shfl_xor(ss, m);
    if (l16 == 0) qinv[tg] = 1.f / fmaxf(sqrtf(ss), 1e-12f);
  }
  __syncthreads();
  for (int r = tid; r < 280; r += 256) {
    const float* kn = ws + OFF_KEYS + r*260;
    float acc[12];
    #pragma unroll
    for (int i = 0; i < 12; ++i) acc[i] = 0.f;
    for (int k = 0; k < 260; ++k) {
      float kv = kn[k];
      #pragma unroll
      for (int i = 0; i < 12; ++i) acc[i] += lat[i][k]*kv;
    }
    #pragma unroll
    for (int i = 0; i < 12; ++i) sc[i][r] = acc[i]*qinv[i];
  }
  __syncthreads();
  if (tg < 12) {
    float mx = -1e30f;
    for (int r = l16; r < 280; r += 16) mx = fmaxf(mx, sc[tg][r]);
    #pragma unroll
    for (int m = 8; m; m >>= 1) mx = fmaxf(mx, __shfl_xor(mx, m));
    float sum = 0;
    for (int r = l16; r < 280; r += 16) { float e = expf(sc[tg][r]-mx); sc[tg][r] = e; sum += e; }
    #pragma unroll
    for (int m = 8; m; m >>= 1) sum += __shfl_xor(sum, m);
    float inv = 1.f/sum;
    for (int r = l16; r < 280; r += 16) sc[tg][r] *= inv;
  }
  __syncthreads();
  for (int dd = tid; dd < 260; dd += 256) {
    float acc[12];
    #pragma unroll
    for (int i = 0; i < 12; ++i) acc[i] = 0.f;
    for (int r = 0; r < 280; ++r) {
      float rv = rel_vals[r*260 + dd];
      #pragma unroll
      for (int i = 0; i < 12; ++i) acc[i] += sc[i][r]*rv;
    }
    #pragma unroll
    for (int i = 0; i < 12; ++i) ctx[i][dd] = acc[i];
  }
  __syncthreads();
  for (int dd = tid; dd < 260; dd += 256) {
    float acc[12];
    float pb = pfc_b[dd];
    #pragma unroll
    for (int i = 0; i < 12; ++i) acc[i] = pb;
    const float* wt = ws + OFF_PFCT;
    for (int k = 0; k < 260; ++k) {
      float w1 = wt[k*260 + dd];
      #pragma unroll
      for (int i = 0; i < 12; ++i) acc[i] += lat[i][k]*w1;
    }
    for (int k = 0; k < 260; ++k) {
      float w2 = wt[(260+k)*260 + dd];
      #pragma unroll
      for (int i = 0; i < 12; ++i) acc[i] += ctx[i][k]*w2;
    }
    #pragma unroll
    for (int i = 0; i < 12; ++i) zb[i][dd] = acc[i];
  }
  __syncthreads();
  if (tg < 12) {
    float s1 = 0, s2 = 0;
    for (int k = l16; k < 260; k += 16) { float v = zb[tg][k]; s1 += v; s2 += v*v; }
    #pragma unroll
    for (int m = 8; m; m >>= 1) { s1 += __shfl_xor(s1,m); s2 += __shfl_xor(s2,m); }
    if (l16 == 0) {
      float mm = s1*(1.f/260.f);
      mu[tg] = mm;
      rstd[tg] = rsqrtf(s2*(1.f/260.f) - mm*mm + 1e-5f);
    }
  }
  __syncthreads();
  for (int dd = tid; dd < 260; dd += 256) {
    float g = pfc_g[dd], b = pfc_beta[dd];
    #pragma unroll
    for (int i = 0; i < 12; ++i) {
      float v = (zb[i][dd]-mu[i])*rstd[i]*g + b;
      float ge = 0.5f*v*(1.f + erff(v*0.70710678118654752f));
      ws[OFF_OUTS + (i*2048 + t)*260 + dd] = ge;
    }
  }
}

// ============ K5: fused LN + logits GEMM (8 rows per WG) ============
__global__ __launch_bounds__(256) void k5_logits(
    const float* __restrict__ on_g, const float* __restrict__ on_b,
    const float* __restrict__ gain, float* __restrict__ ws,
    float* __restrict__ out) {
  int bid = blockIdx.x, tid = threadIdx.x;
  __shared__ float nl[8][260];
  __shared__ float red[4];
  float gn = gain[0];
  float og0 = on_g[tid], ob0 = on_b[tid];
  float og1 = (tid < 4) ? on_g[256+tid] : 0.f;
  float ob1 = (tid < 4) ? on_b[256+tid] : 0.f;
  for (int ii = 0; ii < 8; ++ii) {
    int m = bid*8 + ii;
    const float* row = ws + OFF_OUTS + m*260;
    float v0 = row[tid];
    float v1 = (tid < 4) ? row[256+tid] : 0.f;
    float s1 = block_sum256(v0 + v1, red);
    float s2 = block_sum256(v0*v0 + v1*v1, red);
    float mm = s1*(1.f/260.f);
    float rs = rsqrtf(s2*(1.f/260.f) - mm*mm + 1e-5f);
    nl[ii][tid] = (v0-mm)*rs*og0 + ob0;
    if (tid < 4) nl[ii][256+tid] = (v1-mm)*rs*og1 + ob1;
  }
  __syncthreads();
  float acc[8];
  #pragma unroll
  for (int ii = 0; ii < 8; ++ii) acc[ii] = 0.f;
  const float* st = ws + OFF_SNT;
  for (int k = 0; k < 260; ++k) {
    float wv = st[k*256 + tid];
    #pragma unroll
    for (int ii = 0; ii < 8; ++ii) acc[ii] += nl[ii][k]*wv;
  }
  #pragma unroll
  for (int ii = 0; ii < 8; ++ii)
    out[(bid*8 + ii)*256 + tid] = acc[ii]*gn;
}

// ============================ launch ============================
extern "C" void kernel_launch(void* const* d_in, const int* in_sizes, int n_in,
                              void* d_out, int out_size, void* d_ws, size_t ws_size,
                              hipStream_t stream) {
  const int*   x        = (const int*)  d_in[0];
  const float* h_f      = (const float*)d_in[1];
  const float* h_mono   = (const float*)d_in[2];
  const int*   surprise = (const int*)  d_in[3];
  const int*   dsteps   = (const int*)  d_in[4];
  const float* soma_w   = (const float*)d_in[5];
  const float* gWih     = (const float*)d_in[6];
  const float* gWhh     = (const float*)d_in[7];
  const float* gbih     = (const float*)d_in[8];
  const float* gbhh     = (const float*)d_in[9];
  const float* wWih     = (const float*)d_in[10];
  const float* wWhh     = (const float*)d_in[11];
  const float* wbih     = (const float*)d_in[12];
  const float* wbhh     = (const float*)d_in[13];
  const float* vgW      = (const float*)d_in[14];
  const float* vgb      = (const float*)d_in[15];
  const float* rel_keys = (const float*)d_in[16];
  const float* rel_vals = (const float*)d_in[17];
  const float* pfc_W    = (const float*)d_in[18];
  const float* pfc_b    = (const float*)d_in[19];
  const float* pfc_g    = (const float*)d_in[20];
  const float* pfc_beta = (const float*)d_in[21];
  const float* on_g     = (const float*)d_in[22];
  const float* on_b     = (const float*)d_in[23];
  const float* gain     = (const float*)d_in[24];
  float* out = (float*)d_out;
  float* ws  = (float*)d_ws;
  if (ws_size < (size_t)WS_FLOATS * sizeof(float)) return;  // fail loudly (poisoned out)
  int* flags1 = (int*)(ws + OFF_OUTS);          // dead region during scans
  int* flags2 = flags1 + NB1*FLAG_STRIDE;
  hipMemsetAsync(flags1, 0, NFLAG_INTS*sizeof(int), stream);
  k0_prep  <<<1312, 256, 0, stream>>>(soma_w, gWih, gbih, rel_keys, pfc_W, ws);
  k2_scan1 <<<NB1, 1024, 0, stream>>>(x, h_f, gWhh, gbhh, ws, flags1, out);
  k3_scan2 <<<NB1, 1024, 0, stream>>>(h_mono, wWih, wWhh, wbih, wbhh, vgW, vgb,
                                      surprise, dsteps, ws, flags2, out);
  k4_tail  <<<2048, 256, 0, stream>>>(rel_vals, pfc_b, pfc_g, pfc_beta, ws);
  k5_logits<<<3072, 256, 0, stream>>>(on_g, on_b, gain, ws, out);
}

// Round 5
// 35587.790 us; speedup vs baseline: 2.5974x; 2.5974x over previous
//
#include <hip/hip_runtime.h>
#include <math.h>

// ---------------- problem constants ----------------
// B=12, T=2048, D=260, V=256, R=280, 3D=780
// scan1: 12 batch-groups x 5 WGs (52 dims each)   = 60 WGs x 1024 thr
// scan2: 12 batch-groups x 9 WGs (8x32 + 1x4 dims) = 108 WGs x 1024 thr

// ---------------- workspace layout (float offsets) ----------------
#define OFF_XTAB  0            // [256][780]  soma_w@Wih.T+bih table
#define OFF_KEYS  199680       // [280][260]  l2norm(rel_keys)
#define OFF_SNT   272480       // [260][256]  l2norm(soma_w) transposed
#define OFF_PFCT  339040       // [520][260]  pfc_W transposed
#define OFF_PF    474240       // [2048][12][260] p_f, overlaid later by latf
#define OFF_OUTS  6864000      // [12][2048][260] outs
#define OFF_HBUF  13253760     // [2][12][260] scan1 h dbuf; then k3 flags + will_acc
#define OFF_LATB  13260000     // k2 flags; then [2][12][260] scan2 latent dbuf
#define OFF_HMB   13266240     // [2][12][260] scan2 h_mono dbuf
#define WS_FLOATS 13272544

#define FLAG_STRIDE 32
#define ACC_OFF 6144           // will accumulator, int/float index inside HBUF region

// ---------------- output layout (float offsets) ----------------
#define OUT_HF 6291456
#define OUT_HM 6294576
#define OUT_DS 6297696

// write-through (coherence-point) scalar ops: relaxed agent atomics.
__device__ inline void st_wt(float* p, float v) {
  __hip_atomic_store(p, v, __ATOMIC_RELAXED, __HIP_MEMORY_SCOPE_AGENT);
}
__device__ inline float ld_wt(const float* p) {
  return __hip_atomic_load(p, __ATOMIC_RELAXED, __HIP_MEMORY_SCOPE_AGENT);
}

__device__ inline float block_sum256(float v, float* red) {
  #pragma unroll
  for (int m = 32; m; m >>= 1) v += __shfl_xor(v, m);
  int w = threadIdx.x >> 6;
  __syncthreads();
  if ((threadIdx.x & 63) == 0) red[w] = v;
  __syncthreads();
  return red[0] + red[1] + red[2] + red[3];
}

// per-group barrier: post my flag, wait for the nsub flags of my group.
__device__ inline void post_and_wait(int* flags, int slotbase, int sub, int nsub,
                                     int target, bool skip_wait) {
  __syncthreads();
  int tid = threadIdx.x;
  if (tid == 0) {
    asm volatile("s_waitcnt vmcnt(0)" ::: "memory");
    __hip_atomic_store(&flags[(slotbase + sub)*FLAG_STRIDE], target,
                       __ATOMIC_RELAXED, __HIP_MEMORY_SCOPE_AGENT);
  }
  if (!skip_wait) {
    if (tid < 64) {
      int fi = (slotbase + tid)*FLAG_STRIDE;
      bool act = tid < nsub;
      for (;;) {
        int v = act ? __hip_atomic_load(&flags[fi], __ATOMIC_RELAXED,
                                        __HIP_MEMORY_SCOPE_AGENT)
                    : 0x7fffffff;
        if (__all(v >= target)) break;
      }
    }
    __syncthreads();
  }
}

// ============ K0: prep tables (xtab, keys_n, soma_n^T, pfc_W^T) ============
__global__ __launch_bounds__(256) void k0_prep(
    const float* __restrict__ soma_w, const float* __restrict__ gWih,
    const float* __restrict__ gbih, const float* __restrict__ rel_keys,
    const float* __restrict__ pfc_W, float* __restrict__ ws) {
  int bid = blockIdx.x, tid = threadIdx.x;
  __shared__ float row[260];
  __shared__ float red[4];
  if (bid < 256) {                    // xin table row v
    int v = bid;
    row[tid] = soma_w[v*260 + tid];
    if (tid < 4) row[256+tid] = soma_w[v*260 + 256 + tid];
    __syncthreads();
    for (int n = tid; n < 780; n += 256) {
      const float* w = gWih + n*260;
      float acc = gbih[n];
      for (int k = 0; k < 260; ++k) acc += row[k]*w[k];
      ws[OFF_XTAB + v*780 + n] = acc;
    }
  } else if (bid < 536) {             // keys_n row r
    int r = bid - 256;
    row[tid] = rel_keys[r*260 + tid];
    if (tid < 4) row[256+tid] = rel_keys[r*260 + 256 + tid];
    __syncthreads();
    float v0 = row[tid], v1 = (tid < 4) ? row[256+tid] : 0.f;
    float ss = block_sum256(v0*v0 + v1*v1, red);
    float sc = 1.f / fmaxf(sqrtf(ss), 1e-12f);
    ws[OFF_KEYS + r*260 + tid] = v0*sc;
    if (tid < 4) ws[OFF_KEYS + r*260 + 256 + tid] = v1*sc;
  } else if (bid < 792) {             // soma_n transposed, col v
    int v = bid - 536;
    row[tid] = soma_w[v*260 + tid];
    if (tid < 4) row[256+tid] = soma_w[v*260 + 256 + tid];
    __syncthreads();
    float v0 = row[tid], v1 = (tid < 4) ? row[256+tid] : 0.f;
    float ss = block_sum256(v0*v0 + v1*v1, red);
    float sc = 1.f / fmaxf(sqrtf(ss), 1e-12f);
    ws[OFF_SNT + tid*256 + v] = v0*sc;
    if (tid < 4) ws[OFF_SNT + (256+tid)*256 + v] = v1*sc;
  } else {                            // pfc_W transpose row kk
    int kk = bid - 792;               // 0..519
    for (int d = tid; d < 260; d += 256)
      ws[OFF_PFCT + kk*260 + d] = pfc_W[d*520 + kk];
  }
}

// ============ K2: scan1 (GRU over T), per-batch groups of 5 WGs ============
__global__ __launch_bounds__(1024) void k2_scan1(
    const int* __restrict__ x, const float* __restrict__ h_f,
    const float* __restrict__ gWhh, const float* __restrict__ gbhh,
    float* __restrict__ ws, int* __restrict__ flags, float* __restrict__ out) {
  int wid = blockIdx.x, tid = threadIdx.x;
  int b = wid / 5, sub = wid - b*5;
  int d0 = sub*52;
  int grp = tid >> 4, l16 = tid & 15;
  int klo = l16*17;                    // 16 lanes x 17 = 272 >= 260 (pad 0)
  bool act = grp < 52;
  int dd = d0 + (act ? grp : 0);
  float w1[3][17];
  #pragma unroll
  for (int g = 0; g < 3; ++g) {
    const float* wr = gWhh + (g*260 + dd)*260;
    #pragma unroll
    for (int kk = 0; kk < 17; ++kk) {
      int k = klo + kk;
      w1[g][kk] = (act && k < 260) ? wr[k] : 0.f;
    }
  }
  __shared__ float hsh[320];
  __shared__ float gl[52][3];
  __shared__ float bhh_l[52][3];
  if (tid >= 260 && tid < 320) hsh[tid] = 0.f;
  if (tid < 156) {
    int dl = tid/3, g2 = tid - dl*3;
    bhh_l[dl][g2] = gbhh[g2*260 + d0 + dl];
  }
  float* hbuf = ws + OFF_HBUF;
  float* pf   = ws + OFF_PF;
  const float* xtab = ws + OFF_XTAB;
  int slotbase = b*8;
  int p = 0;
  __syncthreads();
  for (int t = 0; t < 2048; ++t) {
    if (t == 0) {
      if (tid < 260) hsh[tid] = h_f[b*260 + tid];
    } else {
      if (tid < 260) hsh[tid] = ld_wt(hbuf + p*3120 + b*260 + tid);
    }
    __syncthreads();
    if (act) {
      float a0 = 0.f, a1 = 0.f, a2 = 0.f;
      const float* hp = &hsh[klo];
      #pragma unroll
      for (int kk = 0; kk < 17; ++kk) {
        float hv = hp[kk];
        a0 += w1[0][kk]*hv; a1 += w1[1][kk]*hv; a2 += w1[2][kk]*hv;
      }
      #pragma unroll
      for (int m = 8; m; m >>= 1) {
        a0 += __shfl_xor(a0, m); a1 += __shfl_xor(a1, m); a2 += __shfl_xor(a2, m);
      }
      if (l16 == 0) { gl[grp][0] = a0; gl[grp][1] = a1; gl[grp][2] = a2; }
    }
    __syncthreads();
    if (tid < 52) {
      int d = d0 + tid;
      int xi = x[b*2048 + t];
      const float* xrow = xtab + xi*780;
      float xr = xrow[d], xz = xrow[260+d], xn = xrow[520+d];
      float hr = gl[tid][0] + bhh_l[tid][0];
      float hz = gl[tid][1] + bhh_l[tid][1];
      float hn = gl[tid][2] + bhh_l[tid][2];
      float rg = 1.f/(1.f + expf(-(xr+hr)));
      float zg = 1.f/(1.f + expf(-(xz+hz)));
      float ng = tanhf(xn + rg*hn);
      float hprev = hsh[d];
      float hnew = (1.f - zg)*ng + zg*hprev;
      st_wt(hbuf + (p^1)*3120 + b*260 + d, hnew);
      pf[(t*12 + b)*260 + d] = hnew;              // normal store, read post-boundary
      if (t == 2047) out[OUT_HF + b*260 + d] = hnew;
    }
    post_and_wait(flags, slotbase, sub, 5, t+1, t == 2047);
    p ^= 1;
  }
}

// ============ K3: scan2 recurrent core, per-batch groups of 9 WGs ============
// subs 0..7 own 32 dims; sub 8 owns 4 dims (256..259).
// 64 lane-groups: unit u = (dim_local<<1)|src; src 0 = Wih@lat, 1 = Whh@hm.
__global__ __launch_bounds__(1024) void k3_scan2(
    const float* __restrict__ h_mono, const float* __restrict__ wWih,
    const float* __restrict__ wWhh, const float* __restrict__ wbih,
    const float* __restrict__ wbhh, const float* __restrict__ vgW,
    const float* __restrict__ vgb, const int* __restrict__ surprise,
    const int* __restrict__ dsteps, float* __restrict__ ws,
    int* __restrict__ flags, float* __restrict__ will_acc,
    float* __restrict__ out) {
  int wid = blockIdx.x, tid = threadIdx.x;
  int b = wid / 9, sub = wid - b*9;
  int d0 = sub*32;
  int ndim = (sub < 8) ? 32 : 4;
  int ds = dsteps[0];
  if (ds < 1) {                        // ds==0: latf=p_f, h_mono unchanged, no vol
    if (sub == 0 && tid < 260) out[OUT_HM + b*260 + tid] = h_mono[b*260 + tid];
    return;
  }
  int grp = tid >> 4, l16 = tid & 15;
  int klo = l16*17;
  int dl = grp >> 1, src = grp & 1;
  bool act = dl < ndim;
  int dd = d0 + (act ? dl : 0);
  float w3[3][17];
  {
    const float* M = src ? wWhh : wWih;
    #pragma unroll
    for (int g = 0; g < 3; ++g) {
      const float* wr = M + (g*260 + dd)*260;
      #pragma unroll
      for (int kk = 0; kk < 17; ++kk) {
        int k = klo + kk;
        w3[g][kk] = (act && k < 260) ? wr[k] : 0.f;
      }
    }
  }
  __shared__ float latsh[320];
  __shared__ float hmsh[320];
  __shared__ float vgsh[320];
  __shared__ float gl6[32][2][3];
  __shared__ float bih_l[32][3], bhh_l[32][3];
  if (tid < 320) {
    latsh[tid] = 0.f; hmsh[tid] = 0.f;
    vgsh[tid] = (tid < 260) ? vgW[tid] : 0.f;
  }
  if (tid < 96) {
    int dl2 = tid/3, g2 = tid - dl2*3;
    if (dl2 < ndim) {
      bih_l[dl2][g2] = wbih[g2*260 + d0 + dl2];
      bhh_l[dl2][g2] = wbhh[g2*260 + d0 + dl2];
    }
  }
  float sb = logf(fmaxf(1.f, (float)surprise[0]));
  float vgb_sb = vgb[0] + sb;
  float will_local = 0.f;
  float* pf   = ws + OFF_PF;
  float* latb = ws + OFF_LATB;
  float* hmb  = ws + OFF_HMB;
  int slotbase = b*16;
  int p = 0;
  __syncthreads();
  for (int t = 0; t < 2048; ++t) {
    for (int s = 0; s < ds; ++s) {
      bool last = (t == 2047) && (s == ds-1);
      // ---- load state into LDS ----
      if (s == 0) {
        if (tid < 260) latsh[tid] = pf[(t*12 + b)*260 + tid];   // k2 output, normal
        if (t == 0) {
          if (tid >= 512 && tid < 772) hmsh[tid-512] = h_mono[b*260 + (tid-512)];
        } else {
          if (tid >= 512 && tid < 772) hmsh[tid-512] = ld_wt(hmb + p*3120 + b*260 + (tid-512));
        }
      } else {
        if (tid < 260) latsh[tid] = ld_wt(latb + p*3120 + b*260 + tid);
        if (tid >= 512 && tid < 772) hmsh[tid-512] = ld_wt(hmb + p*3120 + b*260 + (tid-512));
      }
      __syncthreads();
      // ---- phase A: 6 dots per dim across lane-groups ----
      if (act) {
        const float* S = src ? hmsh : latsh;
        const float* sp = &S[klo];
        float a0 = 0.f, a1 = 0.f, a2 = 0.f;
        #pragma unroll
        for (int kk = 0; kk < 17; ++kk) {
          float v = sp[kk];
          a0 += w3[0][kk]*v; a1 += w3[1][kk]*v; a2 += w3[2][kk]*v;
        }
        #pragma unroll
        for (int m = 8; m; m >>= 1) {
          a0 += __shfl_xor(a0,m); a1 += __shfl_xor(a1,m); a2 += __shfl_xor(a2,m);
        }
        if (l16 == 0) { gl6[dl][src][0]=a0; gl6[dl][src][1]=a1; gl6[dl][src][2]=a2; }
      }
      __syncthreads();
      // ---- phase B: wave 0 computes vol (all lanes), then combine ----
      if (tid < 64) {
        float pv = vgsh[tid]*latsh[tid] + vgsh[tid+64]*latsh[tid+64]
                 + vgsh[tid+128]*latsh[tid+128] + vgsh[tid+192]*latsh[tid+192]
                 + ((tid < 4) ? vgsh[tid+256]*latsh[tid+256] : 0.f);
        #pragma unroll
        for (int m = 32; m; m >>= 1) pv += __shfl_xor(pv, m);
        float vol = 1.f/(1.f + expf(-(pv + vgb_sb)));
        if (tid == 0) will_local += vol;
        if (tid < ndim) {
          int d = d0 + tid;
          float xr = gl6[tid][0][0] + bih_l[tid][0];
          float xz = gl6[tid][0][1] + bih_l[tid][1];
          float xn = gl6[tid][0][2] + bih_l[tid][2];
          float hr = gl6[tid][1][0] + bhh_l[tid][0];
          float hz = gl6[tid][1][1] + bhh_l[tid][1];
          float hn = gl6[tid][1][2] + bhh_l[tid][2];
          float rg = 1.f/(1.f + expf(-(xr+hr)));
          float zg = 1.f/(1.f + expf(-(xz+hz)));
          float ng = tanhf(xn + rg*hn);
          float hmold = hmsh[d];
          float hmnew = (1.f - zg)*ng + zg*hmold;
          float latnew = latsh[d] + hmnew * vol;
          st_wt(hmb + (p^1)*3120 + b*260 + d, hmnew);
          if (s < ds-1) {
            st_wt(latb + (p^1)*3120 + b*260 + d, latnew);
          } else {
            pf[(t*12 + b)*260 + d] = latnew;      // latf overlay, normal store
            if (t == 2047) out[OUT_HM + b*260 + d] = hmnew;
          }
        }
      }
      post_and_wait(flags, slotbase, sub, 9, t*ds + s + 1, last);
      p ^= 1;
    }
  }
  if (sub == 0 && tid == 0) atomicAdd(will_acc, will_local);
}

// ============ K4: per-t tail (attention + pfc + LN + GELU) + scalars ============
__global__ __launch_bounds__(256) void k4_tail(
    const float* __restrict__ rel_vals, const float* __restrict__ pfc_b,
    const float* __restrict__ pfc_g, const float* __restrict__ pfc_beta,
    const int* __restrict__ dsteps, const float* __restrict__ will_acc,
    float* __restrict__ ws, float* __restrict__ out) {
  int t = blockIdx.x, tid = threadIdx.x;
  int tg = tid >> 4, l16 = tid & 15;
  if (t == 0 && tid == 0) {
    int ds = dsteps[0]; int dsm = ds < 1 ? 1 : ds;
    float W = will_acc[0] * (1.f/12.f);          // sum over (t,s) of vm
    out[OUT_DS]   = (float)ds;
    out[OUT_DS+1] = W * (0.12f/2048.f);
    out[OUT_DS+2] = W / (2048.f * (float)dsm);
  }
  __shared__ float lat[12][260];
  __shared__ float sc[12][280];
  __shared__ float ctx[12][260];
  __shared__ float zb[12][260];
  __shared__ float qinv[12];
  __shared__ float mu[12], rstd[12];
  const float* lsrc = ws + OFF_PF + t*3120;   // latf
  for (int idx = tid; idx < 780; idx += 256)
    ((float4*)lat)[idx] = ((const float4*)lsrc)[idx];
  __syncthreads();
  if (tg < 12) {
    float ss = 0;
    for (int k = l16; k < 260; k += 16) { float v = lat[tg][k]; ss += v*v; }
    #pragma unroll
    for (int m = 8; m; m >>= 1) ss += __shfl_xor(ss, m);
    if (l16 == 0) qinv[tg] = 1.f / fmaxf(sqrtf(ss), 1e-12f);
  }
  __syncthreads();
  for (int r = tid; r < 280; r += 256) {
    const float* kn = ws + OFF_KEYS + r*260;
    float acc[12];
    #pragma unroll
    for (int i = 0; i < 12; ++i) acc[i] = 0.f;
    for (int k = 0; k < 260; ++k) {
      float kv = kn[k];
      #pragma unroll
      for (int i = 0; i < 12; ++i) acc[i] += lat[i][k]*kv;
    }
    #pragma unroll
    for (int i = 0; i < 12; ++i) sc[i][r] = acc[i]*qinv[i];
  }
  __syncthreads();
  if (tg < 12) {
    float mx = -1e30f;
    for (int r = l16; r < 280; r += 16) mx = fmaxf(mx, sc[tg][r]);
    #pragma unroll
    for (int m = 8; m; m >>= 1) mx = fmaxf(mx, __shfl_xor(mx, m));
    float sum = 0;
    for (int r = l16; r < 280; r += 16) { float e = expf(sc[tg][r]-mx); sc[tg][r] = e; sum += e; }
    #pragma unroll
    for (int m = 8; m; m >>= 1) sum += __shfl_xor(sum, m);
    float inv = 1.f/sum;
    for (int r = l16; r < 280; r += 16) sc[tg][r] *= inv;
  }
  __syncthreads();
  for (int dd = tid; dd < 260; dd += 256) {
    float acc[12];
    #pragma unroll
    for (int i = 0; i < 12; ++i) acc[i] = 0.f;
    for (int r = 0; r < 280; ++r) {
      float rv = rel_vals[r*260 + dd];
      #pragma unroll
      for (int i = 0; i < 12; ++i) acc[i] += sc[i][r]*rv;
    }
    #pragma unroll
    for (int i = 0; i < 12; ++i) ctx[i][dd] = acc[i];
  }
  __syncthreads();
  for (int dd = tid; dd < 260; dd += 256) {
    float acc[12];
    float pb = pfc_b[dd];
    #pragma unroll
    for (int i = 0; i < 12; ++i) acc[i] = pb;
    const float* wt = ws + OFF_PFCT;
    for (int k = 0; k < 260; ++k) {
      float w1 = wt[k*260 + dd];
      #pragma unroll
      for (int i = 0; i < 12; ++i) acc[i] += lat[i][k]*w1;
    }
    for (int k = 0; k < 260; ++k) {
      float w2 = wt[(260+k)*260 + dd];
      #pragma unroll
      for (int i = 0; i < 12; ++i) acc[i] += ctx[i][k]*w2;
    }
    #pragma unroll
    for (int i = 0; i < 12; ++i) zb[i][dd] = acc[i];
  }
  __syncthreads();
  if (tg < 12) {
    float s1 = 0, s2 = 0;
    for (int k = l16; k < 260; k += 16) { float v = zb[tg][k]; s1 += v; s2 += v*v; }
    #pragma unroll
    for (int m = 8; m; m >>= 1) { s1 += __shfl_xor(s1,m); s2 += __shfl_xor(s2,m); }
    if (l16 == 0) {
      float mm = s1*(1.f/260.f);
      mu[tg] = mm;
      rstd[tg] = rsqrtf(s2*(1.f/260.f) - mm*mm + 1e-5f);
    }
  }
  __syncthreads();
  for (int dd = tid; dd < 260; dd += 256) {
    float g = pfc_g[dd], b = pfc_beta[dd];
    #pragma unroll
    for (int i = 0; i < 12; ++i) {
      float v = (zb[i][dd]-mu[i])*rstd[i]*g + b;
      float ge = 0.5f*v*(1.f + erff(v*0.70710678118654752f));
      ws[OFF_OUTS + (i*2048 + t)*260 + dd] = ge;
    }
  }
}

// ============ K5: fused LN + logits GEMM (8 rows per WG) ============
__global__ __launch_bounds__(256) void k5_logits(
    const float* __restrict__ on_g, const float* __restrict__ on_b,
    const float* __restrict__ gain, float* __restrict__ ws,
    float* __restrict__ out) {
  int bid = blockIdx.x, tid = threadIdx.x;
  __shared__ float nl[8][260];
  __shared__ float red[4];
  float gn = gain[0];
  float og0 = on_g[tid], ob0 = on_b[tid];
  float og1 = (tid < 4) ? on_g[256+tid] : 0.f;
  float ob1 = (tid < 4) ? on_b[256+tid] : 0.f;
  for (int ii = 0; ii < 8; ++ii) {
    int m = bid*8 + ii;
    const float* row = ws + OFF_OUTS + m*260;
    float v0 = row[tid];
    float v1 = (tid < 4) ? row[256+tid] : 0.f;
    float s1 = block_sum256(v0 + v1, red);
    float s2 = block_sum256(v0*v0 + v1*v1, red);
    float mm = s1*(1.f/260.f);
    float rs = rsqrtf(s2*(1.f/260.f) - mm*mm + 1e-5f);
    nl[ii][tid] = (v0-mm)*rs*og0 + ob0;
    if (tid < 4) nl[ii][256+tid] = (v1-mm)*rs*og1 + ob1;
  }
  __syncthreads();
  float acc[8];
  #pragma unroll
  for (int ii = 0; ii < 8; ++ii) acc[ii] = 0.f;
  const float* st = ws + OFF_SNT;
  for (int k = 0; k < 260; ++k) {
    float wv = st[k*256 + tid];
    #pragma unroll
    for (int ii = 0; ii < 8; ++ii) acc[ii] += nl[ii][k]*wv;
  }
  #pragma unroll
  for (int ii = 0; ii < 8; ++ii)
    out[(bid*8 + ii)*256 + tid] = acc[ii]*gn;
}

// ============================ launch ============================
extern "C" void kernel_launch(void* const* d_in, const int* in_sizes, int n_in,
                              void* d_out, int out_size, void* d_ws, size_t ws_size,
                              hipStream_t stream) {
  const int*   x        = (const int*)  d_in[0];
  const float* h_f      = (const float*)d_in[1];
  const float* h_mono   = (const float*)d_in[2];
  const int*   surprise = (const int*)  d_in[3];
  const int*   dsteps   = (const int*)  d_in[4];
  const float* soma_w   = (const float*)d_in[5];
  const float* gWih     = (const float*)d_in[6];
  const float* gWhh     = (const float*)d_in[7];
  const float* gbih     = (const float*)d_in[8];
  const float* gbhh     = (const float*)d_in[9];
  const float* wWih     = (const float*)d_in[10];
  const float* wWhh     = (const float*)d_in[11];
  const float* wbih     = (const float*)d_in[12];
  const float* wbhh     = (const float*)d_in[13];
  const float* vgW      = (const float*)d_in[14];
  const float* vgb      = (const float*)d_in[15];
  const float* rel_keys = (const float*)d_in[16];
  const float* rel_vals = (const float*)d_in[17];
  const float* pfc_W    = (const float*)d_in[18];
  const float* pfc_b    = (const float*)d_in[19];
  const float* pfc_g    = (const float*)d_in[20];
  const float* pfc_beta = (const float*)d_in[21];
  const float* on_g     = (const float*)d_in[22];
  const float* on_b     = (const float*)d_in[23];
  const float* gain     = (const float*)d_in[24];
  float* out = (float*)d_out;
  float* ws  = (float*)d_ws;
  if (ws_size < (size_t)WS_FLOATS * sizeof(float)) return;  // fail loudly (poisoned out)
  int*   flags1   = (int*)(ws + OFF_LATB);   // k2 flags (LATB dead during k2)
  int*   flags2   = (int*)(ws + OFF_HBUF);   // k3 flags (HBUF dead during k3)
  float* will_acc = ws + OFF_HBUF + ACC_OFF;
  // zero HBUF+LATB+HMB (k2 flags + clean state)
  hipMemsetAsync(ws + OFF_HBUF, 0, (size_t)18720*sizeof(float), stream);
  k0_prep  <<<1312, 256, 0, stream>>>(soma_w, gWih, gbih, rel_keys, pfc_W, ws);
  k2_scan1 <<<60, 1024, 0, stream>>>(x, h_f, gWhh, gbhh, ws, flags1, out);
  // re-zero HBUF region: k3 flags + will accumulator
  hipMemsetAsync(ws + OFF_HBUF, 0, (size_t)6240*sizeof(float), stream);
  k3_scan2 <<<108, 1024, 0, stream>>>(h_mono, wWih, wWhh, wbih, wbhh, vgW, vgb,
                                      surprise, dsteps, ws, flags2, will_acc, out);
  k4_tail  <<<2048, 256, 0, stream>>>(rel_vals, pfc_b, pfc_g, pfc_beta,
                                      dsteps, will_acc, ws, out);
  k5_logits<<<3072, 256, 0, stream>>>(on_g, on_b, gain, ws, out);
}

// Round 8
// 29273.557 us; speedup vs baseline: 3.1576x; 1.2157x over previous
//
#include <hip/hip_runtime.h>
#include <math.h>

// ---------------- problem constants ----------------
// B=12, T=2048, D=260, V=256, R=280, 3D=780
// fused scan kernel: wid<60  -> scan1 role, 12 groups x 5 WGs (52 dims each)
//                    wid>=60 -> scan2 role, 12 groups x 9 WGs (8x32 + 4 dims)

// ---------------- workspace layout (float offsets) ----------------
#define OFF_XTAB  0            // [256][780]  soma_w@Wih.T+bih table
#define OFF_KEYS  199680       // [280][260]  l2norm(rel_keys)
#define OFF_SNT   272480       // [260][256]  l2norm(soma_w) transposed
#define OFF_PFCT  339040       // [520][260]  pfc_W transposed
#define OFF_PF    474240       // [2048][12][260] p_f, overlaid by latf
#define OFF_OUTS  6864000      // [12][2048][260] outs
#define OFF_HBUF  13253760     // [2][12][260] scan1 h mailbox
#define OFF_LATB  13260000     // flags (5376 ints) + will_acc (at +6000)
#define OFF_HMB   13266240     // [2][12][260] scan2 hm mailbox
#define WS_FLOATS 13272544

#define S2OFF 1920             // scan2 flag base (ints) within ctl

// ---------------- output layout (float offsets) ----------------
#define OUT_HF 6291456
#define OUT_HM 6294576
#define OUT_DS 6297696

// write-through (coherence-point) ops: relaxed agent atomics (R5-proven).
__device__ inline void st_wt(float* p, float v) {
  __hip_atomic_store(p, v, __ATOMIC_RELAXED, __HIP_MEMORY_SCOPE_AGENT);
}
__device__ inline float ld_wt(const float* p) {
  return __hip_atomic_load(p, __ATOMIC_RELAXED, __HIP_MEMORY_SCOPE_AGENT);
}
__device__ inline int ld_agi(const int* p) {
  return __hip_atomic_load(p, __ATOMIC_RELAXED, __HIP_MEMORY_SCOPE_AGENT);
}
__device__ inline void st_agi(int* p, int v) {
  __hip_atomic_store(p, v, __ATOMIC_RELAXED, __HIP_MEMORY_SCOPE_AGENT);
}

__device__ inline float block_sum256(float v, float* red) {
  #pragma unroll
  for (int m = 32; m; m >>= 1) v += __shfl_xor(v, m);
  int w = threadIdx.x >> 6;
  __syncthreads();
  if ((threadIdx.x & 63) == 0) red[w] = v;
  __syncthreads();
  return red[0] + red[1] + red[2] + red[3];
}

// scan1 barrier (R5-proven shape): post my flag, poll my group's 5 flags
__device__ inline void s1_post_wait(int* fl, int sub, int target, bool skip) {
  __syncthreads();
  int tid = threadIdx.x;
  if (tid == 0) {
    asm volatile("s_waitcnt vmcnt(0)" ::: "memory");
    st_agi(fl + sub*32, target);
  }
  if (!skip) {
    if (tid < 5) {
      const int* fp = fl + tid*32;
      while (ld_agi(fp) < target) {}
    }
    __syncthreads();
  }
}

// scan2 barrier: post my flag, poll my 9 group flags; lanes 16..20 also poll
// the producer scan1 group's 5 flags for target s1t (if s1t>0).
__device__ inline void s2_post_wait(int* fl2, const int* fl1, int sub,
                                    int target, int s1t, bool skip) {
  __syncthreads();
  int tid = threadIdx.x;
  if (tid == 0) {
    asm volatile("s_waitcnt vmcnt(0)" ::: "memory");
    st_agi(fl2 + sub*32, target);
  }
  if (!skip) {
    if (tid < 64) {
      const int* fp = nullptr; int tgt = 0;
      if (tid < 9) { fp = fl2 + tid*32; tgt = target; }
      else if (tid >= 16 && tid < 21 && s1t > 0) { fp = fl1 + (tid-16)*32; tgt = s1t; }
      if (fp) { while (ld_agi(fp) < tgt) {} }
    }
    __syncthreads();
  }
}

// ============ K0: prep tables (xtab, keys_n, soma_n^T, pfc_W^T) ============
__global__ __launch_bounds__(256) void k0_prep(
    const float* __restrict__ soma_w, const float* __restrict__ gWih,
    const float* __restrict__ gbih, const float* __restrict__ rel_keys,
    const float* __restrict__ pfc_W, float* __restrict__ ws) {
  int bid = blockIdx.x, tid = threadIdx.x;
  __shared__ float row[260];
  __shared__ float red[4];
  if (bid < 256) {                    // xin table row v
    int v = bid;
    row[tid] = soma_w[v*260 + tid];
    if (tid < 4) row[256+tid] = soma_w[v*260 + 256 + tid];
    __syncthreads();
    for (int n = tid; n < 780; n += 256) {
      const float* w = gWih + n*260;
      float acc = gbih[n];
      for (int k = 0; k < 260; ++k) acc += row[k]*w[k];
      ws[OFF_XTAB + v*780 + n] = acc;
    }
  } else if (bid < 536) {             // keys_n row r
    int r = bid - 256;
    row[tid] = rel_keys[r*260 + tid];
    if (tid < 4) row[256+tid] = rel_keys[r*260 + 256 + tid];
    __syncthreads();
    float v0 = row[tid], v1 = (tid < 4) ? row[256+tid] : 0.f;
    float ss = block_sum256(v0*v0 + v1*v1, red);
    float sc = 1.f / fmaxf(sqrtf(ss), 1e-12f);
    ws[OFF_KEYS + r*260 + tid] = v0*sc;
    if (tid < 4) ws[OFF_KEYS + r*260 + 256 + tid] = v1*sc;
  } else if (bid < 792) {             // soma_n transposed, col v
    int v = bid - 536;
    row[tid] = soma_w[v*260 + tid];
    if (tid < 4) row[256+tid] = soma_w[v*260 + 256 + tid];
    __syncthreads();
    float v0 = row[tid], v1 = (tid < 4) ? row[256+tid] : 0.f;
    float ss = block_sum256(v0*v0 + v1*v1, red);
    float sc = 1.f / fmaxf(sqrtf(ss), 1e-12f);
    ws[OFF_SNT + tid*256 + v] = v0*sc;
    if (tid < 4) ws[OFF_SNT + (256+tid)*256 + v] = v1*sc;
  } else {                            // pfc_W transpose row kk
    int kk = bid - 792;               // 0..519
    for (int d = tid; d < 260; d += 256)
      ws[OFF_PFCT + kk*260 + d] = pfc_W[d*520 + kk];
  }
}

// ============ K23: fused scan1 + scan2 (producer-consumer) ============
__global__ __launch_bounds__(1024) void k23_scans(
    const int* __restrict__ x, const float* __restrict__ h_f,
    const float* __restrict__ gWhh, const float* __restrict__ gbhh,
    const float* __restrict__ h_mono, const float* __restrict__ wWih,
    const float* __restrict__ wWhh, const float* __restrict__ wbih,
    const float* __restrict__ wbhh, const float* __restrict__ vgW,
    const float* __restrict__ vgb, const int* __restrict__ surprise,
    const int* __restrict__ dsteps, float* __restrict__ ws,
    int* __restrict__ ctl, float* __restrict__ will_acc,
    float* __restrict__ out) {
  int wid = blockIdx.x, tid = threadIdx.x;
  float* pf = ws + OFF_PF;

  if (wid < 60) {
    // ---------------- scan1 role (R5 k2, pf via write-through) ----------------
    int b = wid / 5, sub = wid - b*5;
    int d0 = sub*52;
    int* fl = ctl + b*(5*32);
    int grp = tid >> 4, l16 = tid & 15;
    int klo = l16*17;
    bool act = grp < 52;
    int dd = d0 + (act ? grp : 0);
    float w1[3][17];
    #pragma unroll
    for (int gg = 0; gg < 3; ++gg) {
      const float* wr = gWhh + (gg*260 + dd)*260;
      #pragma unroll
      for (int kk = 0; kk < 17; ++kk) {
        int k = klo + kk;
        w1[gg][kk] = (act && k < 260) ? wr[k] : 0.f;
      }
    }
    __shared__ float hsh[320];
    __shared__ float gl[52][3];
    __shared__ float bhh_l[52][3];
    if (tid >= 260 && tid < 320) hsh[tid] = 0.f;
    if (tid < 156) {
      int dl = tid/3, g2 = tid - dl*3;
      bhh_l[dl][g2] = gbhh[g2*260 + d0 + dl];
    }
    float* hbuf = ws + OFF_HBUF;
    const float* xtab = ws + OFF_XTAB;
    int p = 0;
    __syncthreads();
    for (int t = 0; t < 2048; ++t) {
      if (t == 0) {
        if (tid < 260) hsh[tid] = h_f[b*260 + tid];
      } else {
        if (tid < 260) hsh[tid] = ld_wt(hbuf + p*3120 + b*260 + tid);
      }
      __syncthreads();
      if (act) {
        float a0 = 0.f, a1 = 0.f, a2 = 0.f;
        const float* hp = &hsh[klo];
        #pragma unroll
        for (int kk = 0; kk < 17; ++kk) {
          float hv = hp[kk];
          a0 += w1[0][kk]*hv; a1 += w1[1][kk]*hv; a2 += w1[2][kk]*hv;
        }
        #pragma unroll
        for (int m = 8; m; m >>= 1) {
          a0 += __shfl_xor(a0, m); a1 += __shfl_xor(a1, m); a2 += __shfl_xor(a2, m);
        }
        if (l16 == 0) { gl[grp][0] = a0; gl[grp][1] = a1; gl[grp][2] = a2; }
      }
      __syncthreads();
      if (tid < 52) {
        int d = d0 + tid;
        int xi = x[b*2048 + t];
        const float* xrow = xtab + xi*780;
        float xr = xrow[d], xz = xrow[260+d], xn = xrow[520+d];
        float hr = gl[tid][0] + bhh_l[tid][0];
        float hz = gl[tid][1] + bhh_l[tid][1];
        float hn = gl[tid][2] + bhh_l[tid][2];
        float rg = 1.f/(1.f + expf(-(xr+hr)));
        float zg = 1.f/(1.f + expf(-(xz+hz)));
        float ng = tanhf(xn + rg*hn);
        float hprev = hsh[d];
        float hnew = (1.f - zg)*ng + zg*hprev;
        st_wt(hbuf + (p^1)*3120 + b*260 + d, hnew);
        st_wt(pf + (t*12 + b)*260 + d, hnew);      // consumed intra-kernel by scan2
        if (t == 2047) out[OUT_HF + b*260 + d] = hnew;
      }
      s1_post_wait(fl, sub, t+1, t == 2047);
      p ^= 1;
    }
    return;
  }

  // ---------------- scan2 role (hm-only broadcast + A/sigma recurrences) ----------------
  int w = wid - 60;
  int b = w / 9, sub = w - b*9;
  int d0 = sub*32;
  int ndim = (sub < 8) ? 32 : 4;
  int ds = dsteps[0];
  if (ds < 1) {                        // latf=p_f (scan1's), h_mono unchanged, will=0
    if (sub == 0 && tid < 260) out[OUT_HM + b*260 + tid] = h_mono[b*260 + tid];
    return;
  }
  int* fl2 = ctl + S2OFF + b*(9*32);
  const int* fl1 = ctl + b*(5*32);
  int grp = tid >> 4, l16 = tid & 15;
  int klo = l16*17;
  int dl = grp >> 1, src = grp & 1;
  bool act = dl < ndim;
  int dd = d0 + (act ? dl : 0);
  float w3[3][17];
  {
    const float* M = src ? wWhh : wWih;
    #pragma unroll
    for (int gg = 0; gg < 3; ++gg) {
      const float* wr = M + (gg*260 + dd)*260;
      #pragma unroll
      for (int kk = 0; kk < 17; ++kk) {
        int k = klo + kk;
        w3[gg][kk] = (act && k < 260) ? wr[k] : 0.f;
      }
    }
  }
  __shared__ float vsh[320];          // p_f[t] at s==0
  __shared__ float hmsh[320];
  __shared__ float vgsh[320];
  __shared__ float gl6[32][2][3];
  if (tid < 320) {
    vsh[tid] = 0.f; hmsh[tid] = 0.f;
    vgsh[tid] = (tid < 260) ? vgW[tid] : 0.f;
  }
  // per-lane persistent state (wave 0): biases, A, lat, sigma, volp
  float bih0=0, bih1=0, bih2=0, bhh0=0, bhh1=0, bhh2=0;
  if (tid < ndim) {
    int d = d0 + tid;
    bih0 = wbih[d]; bih1 = wbih[260+d]; bih2 = wbih[520+d];
    bhh0 = wbhh[d]; bhh1 = wbhh[260+d]; bhh2 = wbhh[520+d];
  }
  float A0=0, A1=0, A2=0, latv=0, sigma=0, volp=0, will_local=0;
  float sb = logf(fmaxf(1.f, (float)surprise[0]));
  float vgb_sb = vgb[0] + sb;
  float* hmb = ws + OFF_HMB;
  // wait for scan1 to publish p_f[0]
  if (tid < 5) { const int* fp = fl1 + tid*32; while (ld_agi(fp) < 1) {} }
  __syncthreads();
  for (int t = 0; t < 2048; ++t) {
    for (int s = 0; s < ds; ++s) {
      int r = t*ds + s;
      bool last = (t == 2047) && (s == ds-1);
      // ---- loads: hm broadcast (every round), p_f[t] (s==0 only) ----
      if (r == 0) {
        if (tid < 260) hmsh[tid] = h_mono[b*260 + tid];
      } else {
        if (tid < 260) hmsh[tid] = ld_wt(hmb + (r&1)*3120 + b*260 + tid);
      }
      if (s == 0) {
        if (tid >= 512 && tid < 772) vsh[tid-512] = ld_wt(pf + (t*12 + b)*260 + (tid-512));
      }
      __syncthreads();
      // ---- phase A: 6 dots per dim (src0: Wih @ (s==0?pf:hm); src1: Whh @ hm) ----
      if (act) {
        const float* S = (src == 0 && s == 0) ? vsh : hmsh;
        const float* sp = &S[klo];
        float a0 = 0.f, a1 = 0.f, a2 = 0.f;
        #pragma unroll
        for (int kk = 0; kk < 17; ++kk) {
          float v = sp[kk];
          a0 += w3[0][kk]*v; a1 += w3[1][kk]*v; a2 += w3[2][kk]*v;
        }
        #pragma unroll
        for (int m = 8; m; m >>= 1) {
          a0 += __shfl_xor(a0,m); a1 += __shfl_xor(a1,m); a2 += __shfl_xor(a2,m);
        }
        if (l16 == 0) { gl6[dl][src][0]=a0; gl6[dl][src][1]=a1; gl6[dl][src][2]=a2; }
      }
      __syncthreads();
      // ---- phase B (wave 0): sigma/vol recurrence, gates, hm store ----
      if (tid < 64) {
        float ph = vgsh[tid]*hmsh[tid] + vgsh[tid+64]*hmsh[tid+64]
                 + vgsh[tid+128]*hmsh[tid+128] + vgsh[tid+192]*hmsh[tid+192]
                 + ((tid < 4) ? vgsh[tid+256]*hmsh[tid+256] : 0.f);
        #pragma unroll
        for (int m = 32; m; m >>= 1) ph += __shfl_xor(ph, m);
        if (s == 0) {
          float pp = vgsh[tid]*vsh[tid] + vgsh[tid+64]*vsh[tid+64]
                   + vgsh[tid+128]*vsh[tid+128] + vgsh[tid+192]*vsh[tid+192]
                   + ((tid < 4) ? vgsh[tid+256]*vsh[tid+256] : 0.f);
          #pragma unroll
          for (int m = 32; m; m >>= 1) pp += __shfl_xor(pp, m);
          sigma = pp;
        } else {
          sigma += volp * ph;                  // vg.lat_s = vg.lat_{s-1} + vol_{s-1}*vg.hm_s
        }
        float voln = 1.f/(1.f + expf(-(sigma + vgb_sb)));
        if (tid < ndim) {
          int d = d0 + tid;
          float g0 = gl6[tid][0][0], g1 = gl6[tid][0][1], g2 = gl6[tid][0][2];
          if (s == 0) { A0 = g0; A1 = g1; A2 = g2; latv = vsh[d]; }
          else        { A0 += volp*g0; A1 += volp*g1; A2 += volp*g2; }
          float gi0 = A0 + bih0, gi1 = A1 + bih1, gi2 = A2 + bih2;
          float gh0 = gl6[tid][1][0] + bhh0;
          float gh1 = gl6[tid][1][1] + bhh1;
          float gh2 = gl6[tid][1][2] + bhh2;
          float rg = 1.f/(1.f + expf(-(gi0+gh0)));
          float zg = 1.f/(1.f + expf(-(gi1+gh1)));
          float ng = tanhf(gi2 + rg*gh2);
          float hmo = hmsh[d];
          float hmn = (1.f - zg)*ng + zg*hmo;
          latv += hmn * voln;                  // lat_{s+1}
          st_wt(hmb + ((r+1)&1)*3120 + b*260 + d, hmn);
          if (s == ds-1) {
            pf[(t*12 + b)*260 + d] = latv;     // latf overlay (k4 reads post-boundary)
            if (t == 2047) out[OUT_HM + b*260 + d] = hmn;
          }
        }
        if (sub == 0 && tid == 0) will_local += voln;
        volp = voln;
      }
      int s1t = (s == ds-1 && t < 2047) ? (t+2) : -1;
      s2_post_wait(fl2, fl1, sub, r+1, s1t, last);
    }
  }
  if (sub == 0 && tid == 0) atomicAdd(will_acc, will_local);
}

// ============ K4: per-t tail (attention + pfc + LN + GELU) + scalars ============
__global__ __launch_bounds__(256) void k4_tail(
    const float* __restrict__ rel_vals, const float* __restrict__ pfc_b,
    const float* __restrict__ pfc_g, const float* __restrict__ pfc_beta,
    const int* __restrict__ dsteps, const float* __restrict__ will_acc,
    float* __restrict__ ws, float* __restrict__ out) {
  int t = blockIdx.x, tid = threadIdx.x;
  int tg = tid >> 4, l16 = tid & 15;
  if (t == 0 && tid == 0) {
    int ds = dsteps[0]; int dsm = ds < 1 ? 1 : ds;
    float W = will_acc[0] * (1.f/12.f);
    out[OUT_DS]   = (float)ds;
    out[OUT_DS+1] = W * (0.12f/2048.f);
    out[OUT_DS+2] = W / (2048.f * (float)dsm);
  }
  __shared__ float lat[12][260];
  __shared__ float sc[12][280];
  __shared__ float ctx[12][260];
  __shared__ float zb[12][260];
  __shared__ float qinv[12];
  __shared__ float mu[12], rstd[12];
  const float* lsrc = ws + OFF_PF + t*3120;   // latf
  for (int idx = tid; idx < 780; idx += 256)
    ((float4*)lat)[idx] = ((const float4*)lsrc)[idx];
  __syncthreads();
  if (tg < 12) {
    float ss = 0;
    for (int k = l16; k < 260; k += 16) { float v = lat[tg][k]; ss += v*v; }
    #pragma unroll
    for (int m = 8; m; m >>= 1) ss += __shfl_xor(ss, m);
    if (l16 == 0) qinv[tg] = 1.f / fmaxf(sqrtf(ss), 1e-12f);
  }
  __syncthreads();
  for (int r = tid; r < 280; r += 256) {
    const float* kn = ws + OFF_KEYS + r*260;
    float acc[12];
    #pragma unroll
    for (int i = 0; i < 12; ++i) acc[i] = 0.f;
    for (int k = 0; k < 260; ++k) {
      float kv = kn[k];
      #pragma unroll
      for (int i = 0; i < 12; ++i) acc[i] += lat[i][k]*kv;
    }
    #pragma unroll
    for (int i = 0; i < 12; ++i) sc[i][r] = acc[i]*qinv[i];
  }
  __syncthreads();
  if (tg < 12) {
    float mx = -1e30f;
    for (int r = l16; r < 280; r += 16) mx = fmaxf(mx, sc[tg][r]);
    #pragma unroll
    for (int m = 8; m; m >>= 1) mx = fmaxf(mx, __shfl_xor(mx, m));
    float sum = 0;
    for (int r = l16; r < 280; r += 16) { float e = expf(sc[tg][r]-mx); sc[tg][r] = e; sum += e; }
    #pragma unroll
    for (int m = 8; m; m >>= 1) sum += __shfl_xor(sum, m);
    float inv = 1.f/sum;
    for (int r = l16; r < 280; r += 16) sc[tg][r] *= inv;
  }
  __syncthreads();
  for (int dd = tid; dd < 260; dd += 256) {
    float acc[12];
    #pragma unroll
    for (int i = 0; i < 12; ++i) acc[i] = 0.f;
    for (int r = 0; r < 280; ++r) {
      float rv = rel_vals[r*260 + dd];
      #pragma unroll
      for (int i = 0; i < 12; ++i) acc[i] += sc[i][r]*rv;
    }
    #pragma unroll
    for (int i = 0; i < 12; ++i) ctx[i][dd] = acc[i];
  }
  __syncthreads();
  for (int dd = tid; dd < 260; dd += 256) {
    float acc[12];
    float pb = pfc_b[dd];
    #pragma unroll
    for (int i = 0; i < 12; ++i) acc[i] = pb;
    const float* wt = ws + OFF_PFCT;
    for (int k = 0; k < 260; ++k) {
      float w1 = wt[k*260 + dd];
      #pragma unroll
      for (int i = 0; i < 12; ++i) acc[i] += lat[i][k]*w1;
    }
    for (int k = 0; k < 260; ++k) {
      float w2 = wt[(260+k)*260 + dd];
      #pragma unroll
      for (int i = 0; i < 12; ++i) acc[i] += ctx[i][k]*w2;
    }
    #pragma unroll
    for (int i = 0; i < 12; ++i) zb[i][dd] = acc[i];
  }
  __syncthreads();
  if (tg < 12) {
    float s1 = 0, s2 = 0;
    for (int k = l16; k < 260; k += 16) { float v = zb[tg][k]; s1 += v; s2 += v*v; }
    #pragma unroll
    for (int m = 8; m; m >>= 1) { s1 += __shfl_xor(s1,m); s2 += __shfl_xor(s2,m); }
    if (l16 == 0) {
      float mm = s1*(1.f/260.f);
      mu[tg] = mm;
      rstd[tg] = rsqrtf(s2*(1.f/260.f) - mm*mm + 1e-5f);
    }
  }
  __syncthreads();
  for (int dd = tid; dd < 260; dd += 256) {
    float g = pfc_g[dd], b = pfc_beta[dd];
    #pragma unroll
    for (int i = 0; i < 12; ++i) {
      float v = (zb[i][dd]-mu[i])*rstd[i]*g + b;
      float ge = 0.5f*v*(1.f + erff(v*0.70710678118654752f));
      ws[OFF_OUTS + (i*2048 + t)*260 + dd] = ge;
    }
  }
}

// ============ K5: fused LN + logits GEMM (8 rows per WG) ============
__global__ __launch_bounds__(256) void k5_logits(
    const float* __restrict__ on_g, const float* __restrict__ on_b,
    const float* __restrict__ gain, float* __restrict__ ws,
    float* __restrict__ out) {
  int bid = blockIdx.x, tid = threadIdx.x;
  __shared__ float nl[8][260];
  __shared__ float red[4];
  float gn = gain[0];
  float og0 = on_g[tid], ob0 = on_b[tid];
  float og1 = (tid < 4) ? on_g[256+tid] : 0.f;
  float ob1 = (tid < 4) ? on_b[256+tid] : 0.f;
  for (int ii = 0; ii < 8; ++ii) {
    int m = bid*8 + ii;
    const float* row = ws + OFF_OUTS + m*260;
    float v0 = row[tid];
    float v1 = (tid < 4) ? row[256+tid] : 0.f;
    float s1 = block_sum256(v0 + v1, red);
    float s2 = block_sum256(v0*v0 + v1*v1, red);
    float mm = s1*(1.f/260.f);
    float rs = rsqrtf(s2*(1.f/260.f) - mm*mm + 1e-5f);
    nl[ii][tid] = (v0-mm)*rs*og0 + ob0;
    if (tid < 4) nl[ii][256+tid] = (v1-mm)*rs*og1 + ob1;
  }
  __syncthreads();
  float acc[8];
  #pragma unroll
  for (int ii = 0; ii < 8; ++ii) acc[ii] = 0.f;
  const float* st = ws + OFF_SNT;
  for (int k = 0; k < 260; ++k) {
    float wv = st[k*256 + tid];
    #pragma unroll
    for (int ii = 0; ii < 8; ++ii) acc[ii] += nl[ii][k]*wv;
  }
  #pragma unroll
  for (int ii = 0; ii < 8; ++ii)
    out[(bid*8 + ii)*256 + tid] = acc[ii]*gn;
}

// ============================ launch ============================
extern "C" void kernel_launch(void* const* d_in, const int* in_sizes, int n_in,
                              void* d_out, int out_size, void* d_ws, size_t ws_size,
                              hipStream_t stream) {
  const int*   x        = (const int*)  d_in[0];
  const float* h_f      = (const float*)d_in[1];
  const float* h_mono   = (const float*)d_in[2];
  const int*   surprise = (const int*)  d_in[3];
  const int*   dsteps   = (const int*)  d_in[4];
  const float* soma_w   = (const float*)d_in[5];
  const float* gWih     = (const float*)d_in[6];
  const float* gWhh     = (const float*)d_in[7];
  const float* gbih     = (const float*)d_in[8];
  const float* gbhh     = (const float*)d_in[9];
  const float* wWih     = (const float*)d_in[10];
  const float* wWhh     = (const float*)d_in[11];
  const float* wbih     = (const float*)d_in[12];
  const float* wbhh     = (const float*)d_in[13];
  const float* vgW      = (const float*)d_in[14];
  const float* vgb      = (const float*)d_in[15];
  const float* rel_keys = (const float*)d_in[16];
  const float* rel_vals = (const float*)d_in[17];
  const float* pfc_W    = (const float*)d_in[18];
  const float* pfc_b    = (const float*)d_in[19];
  const float* pfc_g    = (const float*)d_in[20];
  const float* pfc_beta = (const float*)d_in[21];
  const float* on_g     = (const float*)d_in[22];
  const float* on_b     = (const float*)d_in[23];
  const float* gain     = (const float*)d_in[24];
  float* out = (float*)d_out;
  float* ws  = (float*)d_ws;
  if (ws_size < (size_t)WS_FLOATS * sizeof(float)) return;  // fail loudly (poisoned out)
  int*   ctl      = (int*)(ws + OFF_LATB);       // LATB region free (no lat mailbox)
  float* will_acc = ws + OFF_LATB + 6000;
  hipMemsetAsync(ws + OFF_LATB, 0, (size_t)6240*sizeof(float), stream);
  k0_prep  <<<1312, 256, 0, stream>>>(soma_w, gWih, gbih, rel_keys, pfc_W, ws);
  k23_scans<<<168, 1024, 0, stream>>>(x, h_f, gWhh, gbhh, h_mono, wWih, wWhh,
                                      wbih, wbhh, vgW, vgb, surprise, dsteps,
                                      ws, ctl, will_acc, out);
  k4_tail  <<<2048, 256, 0, stream>>>(rel_vals, pfc_b, pfc_g, pfc_beta,
                                      dsteps, will_acc, ws, out);
  k5_logits<<<3072, 256, 0, stream>>>(on_g, on_b, gain, ws, out);
}

// Round 9
// 23185.123 us; speedup vs baseline: 3.9868x; 1.2626x over previous
//
#include <hip/hip_runtime.h>
#include <math.h>

// ---------------- problem constants ----------------
// B=12, T=2048, D=260, V=256, R=280, 3D=780
// k23: wid<60  -> scan1 role, 12 groups x 5 WGs (flags, off critical path)
//      wid>=60 -> scan2 role, 12 groups x 9 WGs (tagged 8B mailbox, no flags)

// ---------------- workspace layout (float offsets) ----------------
#define OFF_XTAB  0            // [256][780]
#define OFF_KEYS  199680       // [280][260]
#define OFF_SNT   272480       // [260][256]
#define OFF_PFCT  339040       // [520][260]
#define OFF_PF    474240       // [2048][12][260] p_f, overlaid by latf
#define OFF_OUTS  6864000      // [12][2048][260] outs (head = ctl during scans)
#define OFF_HBUF  13253760     // [2][12][260] scan1 h mailbox (flag protocol)
#define OFF_HMT   13260000     // [2][12][260] x 8B tagged hm slots (12480 floats)
#define OFF_WILL  13272480     // will accumulator
#define WS_FLOATS 13272544

// ctl at OFF_OUTS: scan1 flags 12*5*32=1920 ints; poison at [1984]
#define CTL_POISON 1984
#define CTL_INTS   2048

// ---------------- output layout (float offsets) ----------------
#define OUT_HF 6291456
#define OUT_HM 6294576
#define OUT_DS 6297696

// ---- proven R5 write-through 4B ops (relaxed agent atomics) ----
__device__ inline void st_wt(float* p, float v) {
  __hip_atomic_store(p, v, __ATOMIC_RELAXED, __HIP_MEMORY_SCOPE_AGENT);
}
__device__ inline float ld_wt(const float* p) {
  return __hip_atomic_load(p, __ATOMIC_RELAXED, __HIP_MEMORY_SCOPE_AGENT);
}
__device__ inline int ld_agi(const int* p) {
  return __hip_atomic_load(p, __ATOMIC_RELAXED, __HIP_MEMORY_SCOPE_AGENT);
}
__device__ inline void st_agi(int* p, int v) {
  __hip_atomic_store(p, v, __ATOMIC_RELAXED, __HIP_MEMORY_SCOPE_AGENT);
}

// ---- 8B tagged mailbox ops: agent scope = sc1 encoding ----
__device__ inline void store_tag(unsigned long long* slot, float v, int tag) {
  union { float f; unsigned int u; } c; c.f = v;
  unsigned long long pv = ((unsigned long long)(unsigned int)tag << 32) | (unsigned long long)c.u;
  asm volatile("global_store_dwordx2 %0, %1, off sc1" :: "v"(slot), "v"(pv) : "memory");
}
__device__ inline float poll_tag(const unsigned long long* slot, int want, int* poison) {
  unsigned long long pv; int spins = 0;
  for (;;) {
    asm volatile("global_load_dwordx2 %0, %1, off sc1\n\ts_waitcnt vmcnt(0)"
                 : "=v"(pv) : "v"(slot) : "memory");
    if ((int)(pv >> 32) >= want) break;
    if ((++spins & 255) == 0) {
      if (ld_agi(poison)) break;
      if (spins >= 4096) { st_agi(poison, 1); break; }
    }
  }
  union { unsigned int u; float f; } c; c.u = (unsigned int)pv;
  return c.f;
}
// capped flag poll
__device__ inline void poll_flag(const int* fp, int target, int* poison) {
  int spins = 0;
  while (ld_agi(fp) < target) {
    if ((++spins & 255) == 0) {
      if (ld_agi(poison)) break;
      if (spins >= 4096) { st_agi(poison, 1); break; }
    }
  }
}

__device__ inline float block_sum256(float v, float* red) {
  #pragma unroll
  for (int m = 32; m; m >>= 1) v += __shfl_xor(v, m);
  int w = threadIdx.x >> 6;
  __syncthreads();
  if ((threadIdx.x & 63) == 0) red[w] = v;
  __syncthreads();
  return red[0] + red[1] + red[2] + red[3];
}

// scan1 barrier (R5/R8-proven): post my flag, poll my group's 5 flags (capped)
__device__ inline void s1_post_wait(int* fl, int* poison, int sub, int target, bool skip) {
  __syncthreads();
  int tid = threadIdx.x;
  if (tid == 0) {
    asm volatile("s_waitcnt vmcnt(0)" ::: "memory");
    st_agi(fl + sub*32, target);
  }
  if (!skip) {
    if (tid < 5) poll_flag(fl + tid*32, target, poison);
    __syncthreads();
  }
}

// ============ K0: prep tables ============
__global__ __launch_bounds__(256) void k0_prep(
    const float* __restrict__ soma_w, const float* __restrict__ gWih,
    const float* __restrict__ gbih, const float* __restrict__ rel_keys,
    const float* __restrict__ pfc_W, float* __restrict__ ws) {
  int bid = blockIdx.x, tid = threadIdx.x;
  __shared__ float row[260];
  __shared__ float red[4];
  if (bid < 256) {
    int v = bid;
    row[tid] = soma_w[v*260 + tid];
    if (tid < 4) row[256+tid] = soma_w[v*260 + 256 + tid];
    __syncthreads();
    for (int n = tid; n < 780; n += 256) {
      const float* w = gWih + n*260;
      float acc = gbih[n];
      for (int k = 0; k < 260; ++k) acc += row[k]*w[k];
      ws[OFF_XTAB + v*780 + n] = acc;
    }
  } else if (bid < 536) {
    int r = bid - 256;
    row[tid] = rel_keys[r*260 + tid];
    if (tid < 4) row[256+tid] = rel_keys[r*260 + 256 + tid];
    __syncthreads();
    float v0 = row[tid], v1 = (tid < 4) ? row[256+tid] : 0.f;
    float ss = block_sum256(v0*v0 + v1*v1, red);
    float sc = 1.f / fmaxf(sqrtf(ss), 1e-12f);
    ws[OFF_KEYS + r*260 + tid] = v0*sc;
    if (tid < 4) ws[OFF_KEYS + r*260 + 256 + tid] = v1*sc;
  } else if (bid < 792) {
    int v = bid - 536;
    row[tid] = soma_w[v*260 + tid];
    if (tid < 4) row[256+tid] = soma_w[v*260 + 256 + tid];
    __syncthreads();
    float v0 = row[tid], v1 = (tid < 4) ? row[256+tid] : 0.f;
    float ss = block_sum256(v0*v0 + v1*v1, red);
    float sc = 1.f / fmaxf(sqrtf(ss), 1e-12f);
    ws[OFF_SNT + tid*256 + v] = v0*sc;
    if (tid < 4) ws[OFF_SNT + (256+tid)*256 + v] = v1*sc;
  } else {
    int kk = bid - 792;
    for (int d = tid; d < 260; d += 256)
      ws[OFF_PFCT + kk*260 + d] = pfc_W[d*520 + kk];
  }
}

// ============ K23: fused scan1 + scan2 ============
__global__ __launch_bounds__(1024) void k23_scans(
    const int* __restrict__ x, const float* __restrict__ h_f,
    const float* __restrict__ gWhh, const float* __restrict__ gbhh,
    const float* __restrict__ h_mono, const float* __restrict__ wWih,
    const float* __restrict__ wWhh, const float* __restrict__ wbih,
    const float* __restrict__ wbhh, const float* __restrict__ vgW,
    const float* __restrict__ vgb, const int* __restrict__ surprise,
    const int* __restrict__ dsteps, float* __restrict__ ws,
    int* __restrict__ ctl, float* __restrict__ will_acc,
    float* __restrict__ out) {
  int wid = blockIdx.x, tid = threadIdx.x;
  float* pf = ws + OFF_PF;
  int* poison = ctl + CTL_POISON;

  if (wid < 60) {
    // ---------------- scan1 role (R8-proven) ----------------
    int b = wid / 5, sub = wid - b*5;
    int d0 = sub*52;
    int* fl = ctl + b*(5*32);
    int grp = tid >> 4, l16 = tid & 15;
    int klo = l16*17;
    bool act = grp < 52;
    int dd = d0 + (act ? grp : 0);
    float w1[3][17];
    #pragma unroll
    for (int gg = 0; gg < 3; ++gg) {
      const float* wr = gWhh + (gg*260 + dd)*260;
      #pragma unroll
      for (int kk = 0; kk < 17; ++kk) {
        int k = klo + kk;
        w1[gg][kk] = (act && k < 260) ? wr[k] : 0.f;
      }
    }
    __shared__ float hsh[320];
    __shared__ float gl[52][3];
    __shared__ float bhh_l[52][3];
    if (tid >= 260 && tid < 320) hsh[tid] = 0.f;
    if (tid < 156) {
      int dl = tid/3, g2 = tid - dl*3;
      bhh_l[dl][g2] = gbhh[g2*260 + d0 + dl];
    }
    float* hbuf = ws + OFF_HBUF;
    const float* xtab = ws + OFF_XTAB;
    int p = 0;
    __syncthreads();
    for (int t = 0; t < 2048; ++t) {
      if (t == 0) {
        if (tid < 260) hsh[tid] = h_f[b*260 + tid];
      } else {
        if (tid < 260) hsh[tid] = ld_wt(hbuf + p*3120 + b*260 + tid);
      }
      __syncthreads();
      if (act) {
        float a0 = 0.f, a1 = 0.f, a2 = 0.f;
        const float* hp = &hsh[klo];
        #pragma unroll
        for (int kk = 0; kk < 17; ++kk) {
          float hv = hp[kk];
          a0 += w1[0][kk]*hv; a1 += w1[1][kk]*hv; a2 += w1[2][kk]*hv;
        }
        #pragma unroll
        for (int m = 8; m; m >>= 1) {
          a0 += __shfl_xor(a0, m); a1 += __shfl_xor(a1, m); a2 += __shfl_xor(a2, m);
        }
        if (l16 == 0) { gl[grp][0] = a0; gl[grp][1] = a1; gl[grp][2] = a2; }
      }
      __syncthreads();
      if (tid < 52) {
        int d = d0 + tid;
        int xi = x[b*2048 + t];
        const float* xrow = xtab + xi*780;
        float xr = xrow[d], xz = xrow[260+d], xn = xrow[520+d];
        float hr = gl[tid][0] + bhh_l[tid][0];
        float hz = gl[tid][1] + bhh_l[tid][1];
        float hn = gl[tid][2] + bhh_l[tid][2];
        float rg = 1.f/(1.f + expf(-(xr+hr)));
        float zg = 1.f/(1.f + expf(-(xz+hz)));
        float ng = tanhf(xn + rg*hn);
        float hprev = hsh[d];
        float hnew = (1.f - zg)*ng + zg*hprev;
        st_wt(hbuf + (p^1)*3120 + b*260 + d, hnew);
        st_wt(pf + (t*12 + b)*260 + d, hnew);
        if (t == 2047) out[OUT_HF + b*260 + d] = hnew;
      }
      s1_post_wait(fl, poison, sub, t+1, t == 2047);
      p ^= 1;
    }
    return;
  }

  // ---------------- scan2 role: tagged 8B mailbox, no group flags ----------------
  int w = wid - 60;
  int b = w / 9, sub = w - b*9;
  int d0 = sub*32;
  int ndim = (sub < 8) ? 32 : 4;
  int ds = dsteps[0];
  if (ds < 1) {
    if (sub == 0 && tid < 260) out[OUT_HM + b*260 + tid] = h_mono[b*260 + tid];
    return;
  }
  const int* fl1 = ctl + b*(5*32);
  int grp = tid >> 4, l16 = tid & 15;
  int klo = l16*17;
  int dl = grp >> 1, src = grp & 1;
  bool act = dl < ndim;
  int dd = d0 + (act ? dl : 0);
  float w3[3][17];
  {
    const float* M = src ? wWhh : wWih;
    #pragma unroll
    for (int gg = 0; gg < 3; ++gg) {
      const float* wr = M + (gg*260 + dd)*260;
      #pragma unroll
      for (int kk = 0; kk < 17; ++kk) {
        int k = klo + kk;
        w3[gg][kk] = (act && k < 260) ? wr[k] : 0.f;
      }
    }
  }
  __shared__ float vsh[320];          // p_f[t] at s==0
  __shared__ float hmsh[320];
  __shared__ float vgsh[320];
  __shared__ float gl6[32][2][3];
  if (tid < 320) {
    vsh[tid] = 0.f; hmsh[tid] = 0.f;
    vgsh[tid] = (tid < 260) ? vgW[tid] : 0.f;
  }
  float bih0=0, bih1=0, bih2=0, bhh0=0, bhh1=0, bhh2=0;
  if (tid < ndim) {
    int d = d0 + tid;
    bih0 = wbih[d]; bih1 = wbih[260+d]; bih2 = wbih[520+d];
    bhh0 = wbhh[d]; bhh1 = wbhh[260+d]; bhh2 = wbhh[520+d];
  }
  float A0=0, A1=0, A2=0, latv=0, sigma=0, volp=0, will_local=0;
  float sb = logf(fmaxf(1.f, (float)surprise[0]));
  float vgb_sb = vgb[0] + sb;
  unsigned long long* hmt = (unsigned long long*)(ws + OFF_HMT);
  __syncthreads();
  for (int t = 0; t < 2048; ++t) {
    for (int s = 0; s < ds; ++s) {
      int r = t*ds + s;
      // ---- acquire inputs: hm via tagged mailbox; pf at s==0 (scan1 flags) ----
      if (r == 0) {
        if (tid < 260) hmsh[tid] = h_mono[b*260 + tid];
      } else {
        if (tid < 260)
          hmsh[tid] = poll_tag(hmt + ((r&1)*12 + b)*260 + tid, r, poison);
      }
      if (s == 0 && tid >= 512 && tid < 772) {
        int q = tid - 512;
        poll_flag(fl1 + (q % 5)*32, t+1, poison);
        vsh[q] = ld_wt(pf + (t*12 + b)*260 + q);
      }
      __syncthreads();
      // ---- phase A: 6 dots per dim ----
      if (act) {
        const float* S = (src == 0 && s == 0) ? vsh : hmsh;
        const float* sp = &S[klo];
        float a0 = 0.f, a1 = 0.f, a2 = 0.f;
        #pragma unroll
        for (int kk = 0; kk < 17; ++kk) {
          float v = sp[kk];
          a0 += w3[0][kk]*v; a1 += w3[1][kk]*v; a2 += w3[2][kk]*v;
        }
        #pragma unroll
        for (int m = 8; m; m >>= 1) {
          a0 += __shfl_xor(a0,m); a1 += __shfl_xor(a1,m); a2 += __shfl_xor(a2,m);
        }
        if (l16 == 0) { gl6[dl][src][0]=a0; gl6[dl][src][1]=a1; gl6[dl][src][2]=a2; }
      }
      __syncthreads();
      // ---- phase B (wave 0): sigma/vol recurrence, gates, tagged store ----
      if (tid < 64) {
        float ph = vgsh[tid]*hmsh[tid] + vgsh[tid+64]*hmsh[tid+64]
                 + vgsh[tid+128]*hmsh[tid+128] + vgsh[tid+192]*hmsh[tid+192]
                 + ((tid < 4) ? vgsh[tid+256]*hmsh[tid+256] : 0.f);
        #pragma unroll
        for (int m = 32; m; m >>= 1) ph += __shfl_xor(ph, m);
        if (s == 0) {
          float pp = vgsh[tid]*vsh[tid] + vgsh[tid+64]*vsh[tid+64]
                   + vgsh[tid+128]*vsh[tid+128] + vgsh[tid+192]*vsh[tid+192]
                   + ((tid < 4) ? vgsh[tid+256]*vsh[tid+256] : 0.f);
          #pragma unroll
          for (int m = 32; m; m >>= 1) pp += __shfl_xor(pp, m);
          sigma = pp;
        } else {
          sigma += volp * ph;
        }
        float voln = 1.f/(1.f + expf(-(sigma + vgb_sb)));
        if (tid < ndim) {
          int d = d0 + tid;
          float g0 = gl6[tid][0][0], g1 = gl6[tid][0][1], g2 = gl6[tid][0][2];
          if (s == 0) { A0 = g0; A1 = g1; A2 = g2; latv = vsh[d]; }
          else        { A0 += volp*g0; A1 += volp*g1; A2 += volp*g2; }
          float gi0 = A0 + bih0, gi1 = A1 + bih1, gi2 = A2 + bih2;
          float gh0 = gl6[tid][1][0] + bhh0;
          float gh1 = gl6[tid][1][1] + bhh1;
          float gh2 = gl6[tid][1][2] + bhh2;
          float rg = 1.f/(1.f + expf(-(gi0+gh0)));
          float zg = 1.f/(1.f + expf(-(gi1+gh1)));
          float ng = tanhf(gi2 + rg*gh2);
          float hmo = hmsh[d];
          float hmn = (1.f - zg)*ng + zg*hmo;
          latv += hmn * voln;
          store_tag(hmt + (((r+1)&1)*12 + b)*260 + d, hmn, r+1);
          if (s == ds-1) {
            pf[(t*12 + b)*260 + d] = latv;     // latf overlay (k4 reads post-boundary)
            if (t == 2047) out[OUT_HM + b*260 + d] = hmn;
          }
        }
        if (sub == 0 && tid == 0) will_local += voln;
        volp = voln;
      }
      __syncthreads();   // protect hmsh/vsh from next round's overwrite
    }
  }
  if (sub == 0 && tid == 0) atomicAdd(will_acc, will_local);
}

// ============ K4: per-t tail + scalars ============
__global__ __launch_bounds__(256) void k4_tail(
    const float* __restrict__ rel_vals, const float* __restrict__ pfc_b,
    const float* __restrict__ pfc_g, const float* __restrict__ pfc_beta,
    const int* __restrict__ dsteps, const float* __restrict__ will_acc,
    float* __restrict__ ws, float* __restrict__ out) {
  int t = blockIdx.x, tid = threadIdx.x;
  int tg = tid >> 4, l16 = tid & 15;
  if (t == 0 && tid == 0) {
    int ds = dsteps[0]; int dsm = ds < 1 ? 1 : ds;
    float W = will_acc[0] * (1.f/12.f);
    out[OUT_DS]   = (float)ds;
    out[OUT_DS+1] = W * (0.12f/2048.f);
    out[OUT_DS+2] = W / (2048.f * (float)dsm);
  }
  __shared__ float lat[12][260];
  __shared__ float sc[12][280];
  __shared__ float ctx[12][260];
  __shared__ float zb[12][260];
  __shared__ float qinv[12];
  __shared__ float mu[12], rstd[12];
  const float* lsrc = ws + OFF_PF + t*3120;
  for (int idx = tid; idx < 780; idx += 256)
    ((float4*)lat)[idx] = ((const float4*)lsrc)[idx];
  __syncthreads();
  if (tg < 12) {
    float ss = 0;
    for (int k = l16; k < 260; k += 16) { float v = lat[tg][k]; ss += v*v; }
    #pragma unroll
    for (int m = 8; m; m >>= 1) ss += __shfl_xor(ss, m);
    if (l16 == 0) qinv[tg] = 1.f / fmaxf(sqrtf(ss), 1e-12f);
  }
  __syncthreads();
  for (int r = tid; r < 280; r += 256) {
    const float* kn = ws + OFF_KEYS + r*260;
    float acc[12];
    #pragma unroll
    for (int i = 0; i < 12; ++i) acc[i] = 0.f;
    for (int k = 0; k < 260; ++k) {
      float kv = kn[k];
      #pragma unroll
      for (int i = 0; i < 12; ++i) acc[i] += lat[i][k]*kv;
    }
    #pragma unroll
    for (int i = 0; i < 12; ++i) sc[i][r] = acc[i]*qinv[i];
  }
  __syncthreads();
  if (tg < 12) {
    float mx = -1e30f;
    for (int r = l16; r < 280; r += 16) mx = fmaxf(mx, sc[tg][r]);
    #pragma unroll
    for (int m = 8; m; m >>= 1) mx = fmaxf(mx, __shfl_xor(mx, m));
    float sum = 0;
    for (int r = l16; r < 280; r += 16) { float e = expf(sc[tg][r]-mx); sc[tg][r] = e; sum += e; }
    #pragma unroll
    for (int m = 8; m; m >>= 1) sum += __shfl_xor(sum, m);
    float inv = 1.f/sum;
    for (int r = l16; r < 280; r += 16) sc[tg][r] *= inv;
  }
  __syncthreads();
  for (int dd = tid; dd < 260; dd += 256) {
    float acc[12];
    #pragma unroll
    for (int i = 0; i < 12; ++i) acc[i] = 0.f;
    for (int r = 0; r < 280; ++r) {
      float rv = rel_vals[r*260 + dd];
      #pragma unroll
      for (int i = 0; i < 12; ++i) acc[i] += sc[i][r]*rv;
    }
    #pragma unroll
    for (int i = 0; i < 12; ++i) ctx[i][dd] = acc[i];
  }
  __syncthreads();
  for (int dd = tid; dd < 260; dd += 256) {
    float acc[12];
    float pb = pfc_b[dd];
    #pragma unroll
    for (int i = 0; i < 12; ++i) acc[i] = pb;
    const float* wt = ws + OFF_PFCT;
    for (int k = 0; k < 260; ++k) {
      float w1 = wt[k*260 + dd];
      #pragma unroll
      for (int i = 0; i < 12; ++i) acc[i] += lat[i][k]*w1;
    }
    for (int k = 0; k < 260; ++k) {
      float w2 = wt[(260+k)*260 + dd];
      #pragma unroll
      for (int i = 0; i < 12; ++i) acc[i] += ctx[i][k]*w2;
    }
    #pragma unroll
    for (int i = 0; i < 12; ++i) zb[i][dd] = acc[i];
  }
  __syncthreads();
  if (tg < 12) {
    float s1 = 0, s2 = 0;
    for (int k = l16; k < 260; k += 16) { float v = zb[tg][k]; s1 += v; s2 += v*v; }
    #pragma unroll
    for (int m = 8; m; m >>= 1) { s1 += __shfl_xor(s1,m); s2 += __shfl_xor(s2,m); }
    if (l16 == 0) {
      float mm = s1*(1.f/260.f);
      mu[tg] = mm;
      rstd[tg] = rsqrtf(s2*(1.f/260.f) - mm*mm + 1e-5f);
    }
  }
  __syncthreads();
  for (int dd = tid; dd < 260; dd += 256) {
    float g = pfc_g[dd], b = pfc_beta[dd];
    #pragma unroll
    for (int i = 0; i < 12; ++i) {
      float v = (zb[i][dd]-mu[i])*rstd[i]*g + b;
      float ge = 0.5f*v*(1.f + erff(v*0.70710678118654752f));
      ws[OFF_OUTS + (i*2048 + t)*260 + dd] = ge;
    }
  }
}

// ============ K5: fused LN + logits GEMM ============
__global__ __launch_bounds__(256) void k5_logits(
    const float* __restrict__ on_g, const float* __restrict__ on_b,
    const float* __restrict__ gain, float* __restrict__ ws,
    float* __restrict__ out) {
  int bid = blockIdx.x, tid = threadIdx.x;
  __shared__ float nl[8][260];
  __shared__ float red[4];
  float gn = gain[0];
  float og0 = on_g[tid], ob0 = on_b[tid];
  float og1 = (tid < 4) ? on_g[256+tid] : 0.f;
  float ob1 = (tid < 4) ? on_b[256+tid] : 0.f;
  for (int ii = 0; ii < 8; ++ii) {
    int m = bid*8 + ii;
    const float* row = ws + OFF_OUTS + m*260;
    float v0 = row[tid];
    float v1 = (tid < 4) ? row[256+tid] : 0.f;
    float s1 = block_sum256(v0 + v1, red);
    float s2 = block_sum256(v0*v0 + v1*v1, red);
    float mm = s1*(1.f/260.f);
    float rs = rsqrtf(s2*(1.f/260.f) - mm*mm + 1e-5f);
    nl[ii][tid] = (v0-mm)*rs*og0 + ob0;
    if (tid < 4) nl[ii][256+tid] = (v1-mm)*rs*og1 + ob1;
  }
  __syncthreads();
  float acc[8];
  #pragma unroll
  for (int ii = 0; ii < 8; ++ii) acc[ii] = 0.f;
  const float* st = ws + OFF_SNT;
  for (int k = 0; k < 260; ++k) {
    float wv = st[k*256 + tid];
    #pragma unroll
    for (int ii = 0; ii < 8; ++ii) acc[ii] += nl[ii][k]*wv;
  }
  #pragma unroll
  for (int ii = 0; ii < 8; ++ii)
    out[(bid*8 + ii)*256 + tid] = acc[ii]*gn;
}

// ============================ launch ============================
extern "C" void kernel_launch(void* const* d_in, const int* in_sizes, int n_in,
                              void* d_out, int out_size, void* d_ws, size_t ws_size,
                              hipStream_t stream) {
  const int*   x        = (const int*)  d_in[0];
  const float* h_f      = (const float*)d_in[1];
  const float* h_mono   = (const float*)d_in[2];
  const int*   surprise = (const int*)  d_in[3];
  const int*   dsteps   = (const int*)  d_in[4];
  const float* soma_w   = (const float*)d_in[5];
  const float* gWih     = (const float*)d_in[6];
  const float* gWhh     = (const float*)d_in[7];
  const float* gbih     = (const float*)d_in[8];
  const float* gbhh     = (const float*)d_in[9];
  const float* wWih     = (const float*)d_in[10];
  const float* wWhh     = (const float*)d_in[11];
  const float* wbih     = (const float*)d_in[12];
  const float* wbhh     = (const float*)d_in[13];
  const float* vgW      = (const float*)d_in[14];
  const float* vgb      = (const float*)d_in[15];
  const float* rel_keys = (const float*)d_in[16];
  const float* rel_vals = (const float*)d_in[17];
  const float* pfc_W    = (const float*)d_in[18];
  const float* pfc_b    = (const float*)d_in[19];
  const float* pfc_g    = (const float*)d_in[20];
  const float* pfc_beta = (const float*)d_in[21];
  const float* on_g     = (const float*)d_in[22];
  const float* on_b     = (const float*)d_in[23];
  const float* gain     = (const float*)d_in[24];
  float* out = (float*)d_out;
  float* ws  = (float*)d_ws;
  if (ws_size < (size_t)WS_FLOATS * sizeof(float)) return;  // fail loudly (poisoned out)
  int*   ctl      = (int*)(ws + OFF_OUTS);       // dead during scans; k4 rewrites
  float* will_acc = ws + OFF_WILL;
  hipMemsetAsync(ctl, 0, CTL_INTS*sizeof(int), stream);
  hipMemsetAsync(ws + OFF_HMT, 0, (size_t)(WS_FLOATS - OFF_HMT)*sizeof(float), stream);
  k0_prep  <<<1312, 256, 0, stream>>>(soma_w, gWih, gbih, rel_keys, pfc_W, ws);
  k23_scans<<<168, 1024, 0, stream>>>(x, h_f, gWhh, gbhh, h_mono, wWih, wWhh,
                                      wbih, wbhh, vgW, vgb, surprise, dsteps,
                                      ws, ctl, will_acc, out);
  k4_tail  <<<2048, 256, 0, stream>>>(rel_vals, pfc_b, pfc_g, pfc_beta,
                                      dsteps, will_acc, ws, out);
  k5_logits<<<3072, 256, 0, stream>>>(on_g, on_b, gain, ws, out);
}